// Round 8
// baseline (352.194 us; speedup 1.0000x reference)
//
#include <hip/hip_runtime.h>
#include <hip/hip_bf16.h>
#include <math.h>

#define N_NODES 50000
#define FDIM 64
#define BETA 0.5f
#define NEG_SLOPE 0.2f

typedef __attribute__((ext_vector_type(8))) short bf16x8;
typedef __attribute__((ext_vector_type(4))) float f32x4;

__device__ __forceinline__ unsigned short f2bf(float f) {
    unsigned u = __float_as_uint(f);
    unsigned r = (u + 0x7FFFu + ((u >> 16) & 1u)) >> 16;
    return (unsigned short)r;
}
__device__ __forceinline__ float bf2f(unsigned short s) {
    return __uint_as_float((unsigned)s << 16);
}

// ---------------------------------------------------------------------------
// Histogram of dst buckets (bucket = dst>>8) with per-block int64/int32
// self-detection (odd dwords of int64 data are all zero since N < 2^31).
__global__ __launch_bounds__(256) void hist_kernel(
    const unsigned int* __restrict__ eiu, const int* __restrict__ ei32,
    const long long* __restrict__ ei64, int* __restrict__ bucketCounts, int E) {
    __shared__ int det;
    __shared__ int h[256];
    int t = threadIdx.x;
    if (t == 0) det = 0;
    h[t] = 0;
    __syncthreads();
    unsigned base = blockIdx.x * 256 + t;
    if (base < (unsigned)E && eiu[2 * base + 1] != 0u) atomicOr(&det, 1);
    __syncthreads();
    bool is32 = det != 0;
    for (int i = blockIdx.x * blockDim.x + t; i < E; i += gridDim.x * blockDim.x) {
        int d = is32 ? ei32[E + i] : (int)ei64[E + i];
        atomicAdd(&h[d >> 8], 1);
    }
    __syncthreads();
    if (h[t]) atomicAdd(&bucketCounts[t], h[t]);
}

// Block-aggregated scatter of packed (src | dlow<<16) into bucket regions.
// Bucket base offsets computed by local scan of global bucketCounts;
// inter-block ordering via zero-initialized global cursors.
#define CHUNK 4096
__global__ __launch_bounds__(256) void scatter_pairs(
    const unsigned int* __restrict__ eiu, const int* __restrict__ ei32,
    const long long* __restrict__ ei64, const int* __restrict__ bucketCounts,
    int* __restrict__ gCursor, unsigned int* __restrict__ pairs, int E) {
    __shared__ int det;
    __shared__ int sc[256], hist[256], base[256], cur[256];
    int t = threadIdx.x;
    if (t == 0) det = 0;
    hist[t] = 0; cur[t] = 0;
    __syncthreads();
    int beg = blockIdx.x * CHUNK;
    int end = min(E, beg + CHUNK);
    {
        int idx = beg + t;
        if (idx < E && eiu[2 * idx + 1] != 0u) atomicOr(&det, 1);
    }
    // local exclusive scan of global bucket counts
    int c = bucketCounts[t];
    sc[t] = c;
    __syncthreads();
    bool is32 = det != 0;
    for (int off = 1; off < 256; off <<= 1) {
        int v = (t >= off) ? sc[t - off] : 0;
        __syncthreads();
        sc[t] += v;
        __syncthreads();
    }
    int bucketExcl = sc[t] - c;
    for (int i = beg + t; i < end; i += 256) {
        int d = is32 ? ei32[E + i] : (int)ei64[E + i];
        atomicAdd(&hist[d >> 8], 1);
    }
    __syncthreads();
    if (hist[t] > 0) base[t] = bucketExcl + atomicAdd(&gCursor[t], hist[t]);
    __syncthreads();
    for (int i = beg + t; i < end; i += 256) {
        int s, d;
        if (is32) { s = ei32[i]; d = ei32[E + i]; }
        else      { s = (int)ei64[i]; d = (int)ei64[E + i]; }
        int b = d >> 8;
        int pos = base[b] + atomicAdd(&cur[b], 1);
        pairs[pos] = (unsigned int)s | ((unsigned int)(d & 255) << 16);
    }
}

// One block per bucket: counting sort by full dst; writes per-node offsets + srcs.
// Bucket range from local scan of global bucketCounts.
__global__ __launch_bounds__(256) void bucket_sort(
    const unsigned int* __restrict__ pairs, const int* __restrict__ bucketCounts,
    int* __restrict__ offsets, int* __restrict__ srcs, int N, int E) {
    __shared__ int scb[256], cnt[256], sc[256], cur[256];
    int b = blockIdx.x, t = threadIdx.x;
    int cb = bucketCounts[t];
    scb[t] = cb;
    __syncthreads();
    for (int off = 1; off < 256; off <<= 1) {
        int v = (t >= off) ? scb[t - off] : 0;
        __syncthreads();
        scb[t] += v;
        __syncthreads();
    }
    int beg = scb[b] - bucketCounts[b];
    int end = scb[b];
    if (b == 0 && t == 0) offsets[N] = E;
    cnt[t] = 0;
    __syncthreads();
    for (int i = beg + t; i < end; i += 256) atomicAdd(&cnt[(pairs[i] >> 16) & 255u], 1);
    __syncthreads();
    sc[t] = cnt[t];
    __syncthreads();
    for (int off = 1; off < 256; off <<= 1) {
        int v = (t >= off) ? sc[t - off] : 0;
        __syncthreads();
        sc[t] += v;
        __syncthreads();
    }
    int excl = sc[t] - cnt[t];
    int node = (b << 8) + t;
    if (node < N) offsets[node] = beg + excl;
    cur[t] = beg + excl;
    __syncthreads();
    for (int i = beg + t; i < end; i += 256) {
        unsigned int p = pairs[i];
        int pos = atomicAdd(&cur[(p >> 16) & 255u], 1);
        srcs[pos] = (int)(p & 0xFFFFu);
    }
}

// ---------------------------------------------------------------------------
// Prep: transpose W and fc_w into bf16 hi/lo, WT[f*64+k] = split(W[k*64+f]).
__global__ __launch_bounds__(256) void prep_weights(
    const float* __restrict__ W, const float* __restrict__ fcw,
    unsigned short* __restrict__ WTh, unsigned short* __restrict__ WTl,
    unsigned short* __restrict__ FTh, unsigned short* __restrict__ FTl) {
    for (int idx = blockIdx.x * 256 + threadIdx.x; idx < 4096; idx += gridDim.x * 256) {
        int k = idx >> 6, f = idx & 63;
        float w = W[idx];
        unsigned short hi = f2bf(w);
        WTh[f * 64 + k] = hi;
        WTl[f * 64 + k] = f2bf(w - bf2f(hi));
        float w2 = fcw[idx];
        unsigned short hi2 = f2bf(w2);
        FTh[f * 64 + k] = hi2;
        FTl[f * 64 + k] = f2bf(w2 - bf2f(hi2));
    }
}

// ---------------------------------------------------------------------------
// Split-bf16 MFMA transform: h = x@W (fp32-accurate via xh*Wh + xh*Wl + xl*Wh).
// hb written as TWO FEATURE PLANES: hb[(plane*N + node)*32 + (f&31)],
// plane = f>>5, so the gather's per-plane working set is 3.2 MB (L2-resident).
__global__ __launch_bounds__(256, 4) void transform_mfma(
    const float* __restrict__ x,
    const unsigned short* __restrict__ WTh, const unsigned short* __restrict__ WTl,
    const float* __restrict__ a_src, const float* __restrict__ a_dst,  // nullable
    const float* __restrict__ bias,                                    // nullable
    unsigned short* __restrict__ hb,  // bf16 split-plane out (layers), nullable
    float* __restrict__ fout,         // fp32 out (FC), nullable
    float* __restrict__ as_, float* __restrict__ ad_, int N) {
    __shared__ __align__(16) unsigned short WThs[64 * 72];
    __shared__ __align__(16) unsigned short WTls[64 * 72];
    int tid = threadIdx.x;
    {
        int row = tid >> 2;            // 0..63
        int ch = (tid & 3) * 16;       // shorts
        uint4 h0 = ((const uint4*)(WTh + row * 64 + ch))[0];
        uint4 h1 = ((const uint4*)(WTh + row * 64 + ch))[1];
        uint4 l0 = ((const uint4*)(WTl + row * 64 + ch))[0];
        uint4 l1 = ((const uint4*)(WTl + row * 64 + ch))[1];
        *((uint4*)(WThs + row * 72 + ch)) = h0;
        *((uint4*)(WThs + row * 72 + ch + 8)) = h1;
        *((uint4*)(WTls + row * 72 + ch)) = l0;
        *((uint4*)(WTls + row * 72 + ch + 8)) = l1;
    }

    int wid = tid >> 6;
    int lane = tid & 63;
    int col = lane & 15;
    int quad = lane >> 4;
    int mbase = blockIdx.x * 64 + wid * 16;

    bf16x8 Ah[2], Al[2];
    int arow = mbase + col;
    const float* xr = x + (size_t)(arow < N ? arow : 0) * FDIM + quad * 8;
#pragma unroll
    for (int ks = 0; ks < 2; ks++) {
        float4 xa = *(const float4*)(xr + ks * 32);
        float4 xb = *(const float4*)(xr + ks * 32 + 4);
        float xv[8] = {xa.x, xa.y, xa.z, xa.w, xb.x, xb.y, xb.z, xb.w};
#pragma unroll
        for (int e = 0; e < 8; e++) {
            unsigned short hi = f2bf(xv[e]);
            Ah[ks][e] = (short)hi;
            Al[ks][e] = (short)f2bf(xv[e] - bf2f(hi));
        }
    }
    __syncthreads();

    f32x4 acc[4];
#pragma unroll
    for (int ft = 0; ft < 4; ft++) acc[ft] = (f32x4){0.f, 0.f, 0.f, 0.f};

#pragma unroll
    for (int ft = 0; ft < 4; ft++) {
        int f = ft * 16 + col;
#pragma unroll
        for (int ks = 0; ks < 2; ks++) {
            int off = f * 72 + ks * 32 + quad * 8;
            bf16x8 Bh = *(const bf16x8*)(WThs + off);
            bf16x8 Bl = *(const bf16x8*)(WTls + off);
            acc[ft] = __builtin_amdgcn_mfma_f32_16x16x32_bf16(Ah[ks], Bh, acc[ft], 0, 0, 0);
            acc[ft] = __builtin_amdgcn_mfma_f32_16x16x32_bf16(Ah[ks], Bl, acc[ft], 0, 0, 0);
            acc[ft] = __builtin_amdgcn_mfma_f32_16x16x32_bf16(Al[ks], Bh, acc[ft], 0, 0, 0);
        }
    }

    if (fout) {
#pragma unroll
        for (int ft = 0; ft < 4; ft++) {
            int f = ft * 16 + col;
            float bv = bias ? bias[f] : 0.f;
#pragma unroll
            for (int r = 0; r < 4; r++) {
                int node = mbase + quad * 4 + r;
                if (node < N) fout[(size_t)node * FDIM + f] = acc[ft][r] + bv;
            }
        }
    }
    if (hb) {
#pragma unroll
        for (int ft = 0; ft < 4; ft++) {
            int f = ft * 16 + col;
            size_t pb = (size_t)(f >> 5) * N;
            int fo = f & 31;
#pragma unroll
            for (int r = 0; r < 4; r++) {
                int node = mbase + quad * 4 + r;
                if (node < N) hb[(pb + node) * 32 + fo] = f2bf(acc[ft][r]);
            }
        }
    }
    if (as_) {
        float asv[4], adv[4];
#pragma unroll
        for (int ft = 0; ft < 4; ft++) {
            asv[ft] = a_src[ft * 16 + col];
            adv[ft] = a_dst[ft * 16 + col];
        }
#pragma unroll
        for (int r = 0; r < 4; r++) {
            float pa = 0.f, pd = 0.f;
#pragma unroll
            for (int ft = 0; ft < 4; ft++) {
                pa = fmaf(acc[ft][r], asv[ft], pa);
                pd = fmaf(acc[ft][r], adv[ft], pd);
            }
#pragma unroll
            for (int off = 1; off <= 8; off <<= 1) {
                pa += __shfl_xor(pa, off, 64);
                pd += __shfl_xor(pd, off, 64);
            }
            int node = mbase + quad * 4 + r;
            if (col == 0 && node < N) { as_[node] = pa; ad_[node] = pd; }
        }
    }
}

// ---------------------------------------------------------------------------
// One wave per (dst, feature-plane). Plane chosen by XCD slot (blockIdx%8:
// 0-3 -> plane 0, 4-7 -> plane 1) so each XCD's L2 holds one 3.2 MB plane.
// 8 edge slots x 8 feat lanes, ushort4 (8B) plane-row loads, nt stream hints.
__global__ __launch_bounds__(256) void gat_gather(
    const unsigned short* __restrict__ hb,
    const float* __restrict__ as_, const float* __restrict__ ad_,
    const int* __restrict__ offsets, const int* __restrict__ srcs,
    const float* __restrict__ bvec, const float* __restrict__ x0,
    float* __restrict__ xout, int N) {
    int b = blockIdx.x;
    int plane = (b >> 2) & 1;              // b&7: 0-3 -> 0, 4-7 -> 1
    int w = (b >> 3) * 4 + (b & 3);
    int dst = w * 4 + (threadIdx.x >> 6);
    if (dst >= N) return;
    int lane = threadIdx.x & 63;
    int eslot = lane >> 3;   // edge slot 0..7
    int q = lane & 7;        // feature quad 0..7 (4 feats each)
    int beg = offsets[dst], end = offsets[dst + 1];
    float adv = ad_[dst];

    f32x4 acc = {0.f, 0.f, 0.f, 0.f};
    float denom = 0.f;
    const unsigned short* hq = hb + (size_t)plane * N * 32 + (q << 2);

#define SLOT(J)                                                              \
    {                                                                        \
        int j_ = (J);                                                        \
        float exj = __shfl(ex, j_, 64);                                      \
        int sj = __shfl(s, j_, 64);                                          \
        ushort4 hv = *(const ushort4*)(hq + (size_t)sj * 32);                \
        acc.x = fmaf(exj, bf2f(hv.x), acc.x);                                \
        acc.y = fmaf(exj, bf2f(hv.y), acc.y);                                \
        acc.z = fmaf(exj, bf2f(hv.z), acc.z);                                \
        acc.w = fmaf(exj, bf2f(hv.w), acc.w);                                \
    }

    for (int cbeg = beg; cbeg < end; cbeg += 64) {
        int i = cbeg + lane;
        float ex = 0.f;
        int s = 0;
        if (i < end) {
            s = __builtin_nontemporal_load(&srcs[i]);
            float e = as_[s] + adv;
            e = e > 0.f ? e : NEG_SLOPE * e;
            ex = __expf(e);
        }
        denom += ex;
        int cnt = min(64, end - cbeg);
        int njj = (cnt + 7) >> 3;
        int jj = 0;
        for (; jj + 4 <= njj; jj += 4) {
            int j0 = (jj << 3) | eslot;
            SLOT(j0); SLOT(j0 + 8); SLOT(j0 + 16); SLOT(j0 + 24);
        }
        for (; jj < njj; jj++) {
            SLOT((jj << 3) | eslot);
        }
    }
#undef SLOT

#pragma unroll
    for (int off = 32; off; off >>= 1) denom += __shfl_xor(denom, off, 64);
#pragma unroll
    for (int off = 8; off <= 32; off <<= 1) {
        acc.x += __shfl_xor(acc.x, off, 64);
        acc.y += __shfl_xor(acc.y, off, 64);
        acc.z += __shfl_xor(acc.z, off, 64);
        acc.w += __shfl_xor(acc.w, off, 64);
    }
    if (eslot == 0) {
        float inv = denom > 0.f ? 1.f / denom : 0.f;
        int fbase = plane * 32 + (q << 2);
        const f32x4* b4p = (const f32x4*)(bvec + fbase);
        f32x4 b4 = *b4p;
        f32x4 xv = __builtin_nontemporal_load((const f32x4*)(x0 + (size_t)dst * FDIM + fbase));
        f32x4 o;
        o.x = BETA * (acc.x * inv + b4.x) + (1.f - BETA) * xv.x;
        o.y = BETA * (acc.y * inv + b4.y) + (1.f - BETA) * xv.y;
        o.z = BETA * (acc.z * inv + b4.z) + (1.f - BETA) * xv.z;
        o.w = BETA * (acc.w * inv + b4.w) + (1.f - BETA) * xv.w;
        __builtin_nontemporal_store(o, (f32x4*)(xout + (size_t)dst * FDIM + fbase));
    }
}

// ---------------------------------------------------------------------------
extern "C" void kernel_launch(void* const* d_in, const int* in_sizes, int n_in,
                              void* d_out, int out_size, void* d_ws, size_t ws_size,
                              hipStream_t stream) {
    const int N = N_NODES;
    const int E = in_sizes[1] / 2;
    const int NB = (N + 255) >> 8;   // 196 buckets

    const float* x     = (const float*)d_in[0];
    const void*  ei    = d_in[1];
    const float* W     = (const float*)d_in[2];
    const float* a_src = (const float*)d_in[3];
    const float* a_dst = (const float*)d_in[4];
    const float* bvec  = (const float*)d_in[5];
    const float* fc_w  = (const float*)d_in[6];
    const float* fc_b  = (const float*)d_in[7];

    float* out = (float*)d_out;                 // [N, F]
    float* x3  = out + (size_t)N * FDIM;        // [N, F] (second output = h)

    char* p = (char*)d_ws;
    auto alloc = [&](size_t bytes) -> void* {
        void* r = (void*)p;
        p += (bytes + 255) & ~(size_t)255;
        return r;
    };
    int*            bCounts  = (int*)alloc(512 * 4);   // counts[256] + gCursor[256]
    unsigned int*   pairs    = (unsigned int*)alloc((size_t)E * 4);
    int*            srcs     = (int*)alloc((size_t)E * 4);
    int*            offsets  = (int*)alloc((size_t)(N + 1) * 4);
    float*          as_      = (float*)alloc((size_t)N * 4);
    float*          ad_      = (float*)alloc((size_t)N * 4);
    unsigned short* hbuf     = (unsigned short*)alloc((size_t)N * FDIM * 2);
    float*          xbuf     = (float*)alloc((size_t)N * FDIM * 4);
    unsigned short* WTh      = (unsigned short*)alloc(4096 * 2);
    unsigned short* WTl      = (unsigned short*)alloc(4096 * 2);
    unsigned short* FTh      = (unsigned short*)alloc(4096 * 2);
    unsigned short* FTl      = (unsigned short*)alloc(4096 * 2);
    int* gCursor = bCounts + 256;

    hipMemsetAsync(bCounts, 0, 512 * 4, stream);

    prep_weights<<<16, 256, 0, stream>>>(W, fc_w, WTh, WTl, FTh, FTl);

    hist_kernel<<<512, 256, 0, stream>>>((const unsigned int*)ei, (const int*)ei,
                                         (const long long*)ei, bCounts, E);
    scatter_pairs<<<(E + CHUNK - 1) / CHUNK, 256, 0, stream>>>(
        (const unsigned int*)ei, (const int*)ei, (const long long*)ei,
        bCounts, gCursor, pairs, E);
    bucket_sort<<<NB, 256, 0, stream>>>(pairs, bCounts, offsets, srcs, N, E);

    int tgrid = (N + 63) / 64;
    int ggrid = 2 * ((N + 3) / 4);   // 2 planes x N dst-waves, 4 waves/block

    // layer 1
    transform_mfma<<<tgrid, 256, 0, stream>>>(x, WTh, WTl, a_src, a_dst, nullptr,
                                              hbuf, nullptr, as_, ad_, N);
    gat_gather<<<ggrid, 256, 0, stream>>>(hbuf, as_, ad_, offsets, srcs, bvec, x, xbuf, N);
    // layer 2
    transform_mfma<<<tgrid, 256, 0, stream>>>(xbuf, WTh, WTl, a_src, a_dst, nullptr,
                                              hbuf, nullptr, as_, ad_, N);
    gat_gather<<<ggrid, 256, 0, stream>>>(hbuf, as_, ad_, offsets, srcs, bvec, x, xbuf, N);
    // layer 3
    transform_mfma<<<tgrid, 256, 0, stream>>>(xbuf, WTh, WTl, a_src, a_dst, nullptr,
                                              hbuf, nullptr, as_, ad_, N);
    gat_gather<<<ggrid, 256, 0, stream>>>(hbuf, as_, ad_, offsets, srcs, bvec, x, x3, N);
    // final fc: out = x3 @ fc_w + fc_b
    transform_mfma<<<tgrid, 256, 0, stream>>>(x3, FTh, FTl, nullptr, nullptr, fc_b,
                                              nullptr, out, nullptr, nullptr, N);
}

// Round 9
// 345.784 us; speedup vs baseline: 1.0185x; 1.0185x over previous
//
#include <hip/hip_runtime.h>
#include <hip/hip_bf16.h>
#include <math.h>

#define N_NODES 50000
#define FDIM 64
#define BETA 0.5f
#define NEG_SLOPE 0.2f

typedef __attribute__((ext_vector_type(8))) short bf16x8;
typedef __attribute__((ext_vector_type(4))) float f32x4;

__device__ __forceinline__ unsigned short f2bf(float f) {
    unsigned u = __float_as_uint(f);
    unsigned r = (u + 0x7FFFu + ((u >> 16) & 1u)) >> 16;
    return (unsigned short)r;
}
__device__ __forceinline__ float bf2f(unsigned short s) {
    return __uint_as_float((unsigned)s << 16);
}

// ---------------------------------------------------------------------------
// Histogram of dst buckets (bucket = dst>>8) with per-block int64/int32
// self-detection (odd dwords of int64 data are all zero since N < 2^31).
__global__ __launch_bounds__(256) void hist_kernel(
    const unsigned int* __restrict__ eiu, const int* __restrict__ ei32,
    const long long* __restrict__ ei64, int* __restrict__ bucketCounts, int E) {
    __shared__ int det;
    __shared__ int h[256];
    int t = threadIdx.x;
    if (t == 0) det = 0;
    h[t] = 0;
    __syncthreads();
    unsigned base = blockIdx.x * 256 + t;
    if (base < (unsigned)E && eiu[2 * base + 1] != 0u) atomicOr(&det, 1);
    __syncthreads();
    bool is32 = det != 0;
    for (int i = blockIdx.x * blockDim.x + t; i < E; i += gridDim.x * blockDim.x) {
        int d = is32 ? ei32[E + i] : (int)ei64[E + i];
        atomicAdd(&h[d >> 8], 1);
    }
    __syncthreads();
    if (h[t]) atomicAdd(&bucketCounts[t], h[t]);
}

// Block-aggregated scatter of packed (src | dlow<<16) into bucket regions.
#define CHUNK 4096
__global__ __launch_bounds__(256) void scatter_pairs(
    const unsigned int* __restrict__ eiu, const int* __restrict__ ei32,
    const long long* __restrict__ ei64, const int* __restrict__ bucketCounts,
    int* __restrict__ gCursor, unsigned int* __restrict__ pairs, int E) {
    __shared__ int det;
    __shared__ int sc[256], hist[256], base[256], cur[256];
    int t = threadIdx.x;
    if (t == 0) det = 0;
    hist[t] = 0; cur[t] = 0;
    __syncthreads();
    int beg = blockIdx.x * CHUNK;
    int end = min(E, beg + CHUNK);
    {
        int idx = beg + t;
        if (idx < E && eiu[2 * idx + 1] != 0u) atomicOr(&det, 1);
    }
    int c = bucketCounts[t];
    sc[t] = c;
    __syncthreads();
    bool is32 = det != 0;
    for (int off = 1; off < 256; off <<= 1) {
        int v = (t >= off) ? sc[t - off] : 0;
        __syncthreads();
        sc[t] += v;
        __syncthreads();
    }
    int bucketExcl = sc[t] - c;
    for (int i = beg + t; i < end; i += 256) {
        int d = is32 ? ei32[E + i] : (int)ei64[E + i];
        atomicAdd(&hist[d >> 8], 1);
    }
    __syncthreads();
    if (hist[t] > 0) base[t] = bucketExcl + atomicAdd(&gCursor[t], hist[t]);
    __syncthreads();
    for (int i = beg + t; i < end; i += 256) {
        int s, d;
        if (is32) { s = ei32[i]; d = ei32[E + i]; }
        else      { s = (int)ei64[i]; d = (int)ei64[E + i]; }
        int b = d >> 8;
        int pos = base[b] + atomicAdd(&cur[b], 1);
        pairs[pos] = (unsigned int)s | ((unsigned int)(d & 255) << 16);
    }
}

// One block per bucket: counting sort by full dst; writes per-node offsets + srcs.
__global__ __launch_bounds__(256) void bucket_sort(
    const unsigned int* __restrict__ pairs, const int* __restrict__ bucketCounts,
    int* __restrict__ offsets, int* __restrict__ srcs, int N, int E) {
    __shared__ int scb[256], cnt[256], sc[256], cur[256];
    int b = blockIdx.x, t = threadIdx.x;
    int cb = bucketCounts[t];
    scb[t] = cb;
    __syncthreads();
    for (int off = 1; off < 256; off <<= 1) {
        int v = (t >= off) ? scb[t - off] : 0;
        __syncthreads();
        scb[t] += v;
        __syncthreads();
    }
    int beg = scb[b] - bucketCounts[b];
    int end = scb[b];
    if (b == 0 && t == 0) offsets[N] = E;
    cnt[t] = 0;
    __syncthreads();
    for (int i = beg + t; i < end; i += 256) atomicAdd(&cnt[(pairs[i] >> 16) & 255u], 1);
    __syncthreads();
    sc[t] = cnt[t];
    __syncthreads();
    for (int off = 1; off < 256; off <<= 1) {
        int v = (t >= off) ? sc[t - off] : 0;
        __syncthreads();
        sc[t] += v;
        __syncthreads();
    }
    int excl = sc[t] - cnt[t];
    int node = (b << 8) + t;
    if (node < N) offsets[node] = beg + excl;
    cur[t] = beg + excl;
    __syncthreads();
    for (int i = beg + t; i < end; i += 256) {
        unsigned int p = pairs[i];
        int pos = atomicAdd(&cur[(p >> 16) & 255u], 1);
        srcs[pos] = (int)(p & 0xFFFFu);
    }
}

// ---------------------------------------------------------------------------
// Prep: transpose W and fc_w into bf16 hi/lo, WT[f*64+k] = split(W[k*64+f]).
__global__ __launch_bounds__(256) void prep_weights(
    const float* __restrict__ W, const float* __restrict__ fcw,
    unsigned short* __restrict__ WTh, unsigned short* __restrict__ WTl,
    unsigned short* __restrict__ FTh, unsigned short* __restrict__ FTl) {
    for (int idx = blockIdx.x * 256 + threadIdx.x; idx < 4096; idx += gridDim.x * 256) {
        int k = idx >> 6, f = idx & 63;
        float w = W[idx];
        unsigned short hi = f2bf(w);
        WTh[f * 64 + k] = hi;
        WTl[f * 64 + k] = f2bf(w - bf2f(hi));
        float w2 = fcw[idx];
        unsigned short hi2 = f2bf(w2);
        FTh[f * 64 + k] = hi2;
        FTl[f * 64 + k] = f2bf(w2 - bf2f(hi2));
    }
}

// ---------------------------------------------------------------------------
// Split-bf16 MFMA transform: h = x@W (fp32-accurate via xh*Wh + xh*Wl + xl*Wh).
// hb written as TWO FEATURE PLANES: hb[(plane*N + node)*32 + (f&31)].
__global__ __launch_bounds__(256, 4) void transform_mfma(
    const float* __restrict__ x,
    const unsigned short* __restrict__ WTh, const unsigned short* __restrict__ WTl,
    const float* __restrict__ a_src, const float* __restrict__ a_dst,  // nullable
    const float* __restrict__ bias,                                    // nullable
    unsigned short* __restrict__ hb,  // bf16 split-plane out (layers), nullable
    float* __restrict__ fout,         // fp32 out (FC), nullable
    float* __restrict__ as_, float* __restrict__ ad_, int N) {
    __shared__ __align__(16) unsigned short WThs[64 * 72];
    __shared__ __align__(16) unsigned short WTls[64 * 72];
    int tid = threadIdx.x;
    {
        int row = tid >> 2;            // 0..63
        int ch = (tid & 3) * 16;       // shorts
        uint4 h0 = ((const uint4*)(WTh + row * 64 + ch))[0];
        uint4 h1 = ((const uint4*)(WTh + row * 64 + ch))[1];
        uint4 l0 = ((const uint4*)(WTl + row * 64 + ch))[0];
        uint4 l1 = ((const uint4*)(WTl + row * 64 + ch))[1];
        *((uint4*)(WThs + row * 72 + ch)) = h0;
        *((uint4*)(WThs + row * 72 + ch + 8)) = h1;
        *((uint4*)(WTls + row * 72 + ch)) = l0;
        *((uint4*)(WTls + row * 72 + ch + 8)) = l1;
    }

    int wid = tid >> 6;
    int lane = tid & 63;
    int col = lane & 15;
    int quad = lane >> 4;
    int mbase = blockIdx.x * 64 + wid * 16;

    bf16x8 Ah[2], Al[2];
    int arow = mbase + col;
    const float* xr = x + (size_t)(arow < N ? arow : 0) * FDIM + quad * 8;
#pragma unroll
    for (int ks = 0; ks < 2; ks++) {
        float4 xa = *(const float4*)(xr + ks * 32);
        float4 xb = *(const float4*)(xr + ks * 32 + 4);
        float xv[8] = {xa.x, xa.y, xa.z, xa.w, xb.x, xb.y, xb.z, xb.w};
#pragma unroll
        for (int e = 0; e < 8; e++) {
            unsigned short hi = f2bf(xv[e]);
            Ah[ks][e] = (short)hi;
            Al[ks][e] = (short)f2bf(xv[e] - bf2f(hi));
        }
    }
    __syncthreads();

    f32x4 acc[4];
#pragma unroll
    for (int ft = 0; ft < 4; ft++) acc[ft] = (f32x4){0.f, 0.f, 0.f, 0.f};

#pragma unroll
    for (int ft = 0; ft < 4; ft++) {
        int f = ft * 16 + col;
#pragma unroll
        for (int ks = 0; ks < 2; ks++) {
            int off = f * 72 + ks * 32 + quad * 8;
            bf16x8 Bh = *(const bf16x8*)(WThs + off);
            bf16x8 Bl = *(const bf16x8*)(WTls + off);
            acc[ft] = __builtin_amdgcn_mfma_f32_16x16x32_bf16(Ah[ks], Bh, acc[ft], 0, 0, 0);
            acc[ft] = __builtin_amdgcn_mfma_f32_16x16x32_bf16(Ah[ks], Bl, acc[ft], 0, 0, 0);
            acc[ft] = __builtin_amdgcn_mfma_f32_16x16x32_bf16(Al[ks], Bh, acc[ft], 0, 0, 0);
        }
    }

    if (fout) {
#pragma unroll
        for (int ft = 0; ft < 4; ft++) {
            int f = ft * 16 + col;
            float bv = bias ? bias[f] : 0.f;
#pragma unroll
            for (int r = 0; r < 4; r++) {
                int node = mbase + quad * 4 + r;
                if (node < N) fout[(size_t)node * FDIM + f] = acc[ft][r] + bv;
            }
        }
    }
    if (hb) {
#pragma unroll
        for (int ft = 0; ft < 4; ft++) {
            int f = ft * 16 + col;
            size_t pb = (size_t)(f >> 5) * N;
            int fo = f & 31;
#pragma unroll
            for (int r = 0; r < 4; r++) {
                int node = mbase + quad * 4 + r;
                if (node < N) hb[(pb + node) * 32 + fo] = f2bf(acc[ft][r]);
            }
        }
    }
    if (as_) {
        float asv[4], adv[4];
#pragma unroll
        for (int ft = 0; ft < 4; ft++) {
            asv[ft] = a_src[ft * 16 + col];
            adv[ft] = a_dst[ft * 16 + col];
        }
#pragma unroll
        for (int r = 0; r < 4; r++) {
            float pa = 0.f, pd = 0.f;
#pragma unroll
            for (int ft = 0; ft < 4; ft++) {
                pa = fmaf(acc[ft][r], asv[ft], pa);
                pd = fmaf(acc[ft][r], adv[ft], pd);
            }
#pragma unroll
            for (int off = 1; off <= 8; off <<= 1) {
                pa += __shfl_xor(pa, off, 64);
                pd += __shfl_xor(pd, off, 64);
            }
            int node = mbase + quad * 4 + r;
            if (col == 0 && node < N) { as_[node] = pa; ad_[node] = pd; }
        }
    }
}

// ---------------------------------------------------------------------------
// One wave per dst: normalized softmax edge weights, fp32, written once.
// Logits bounded -> no max-subtraction needed.
__global__ __launch_bounds__(256) void edge_weights(
    const float* __restrict__ as_, const float* __restrict__ ad_,
    const int* __restrict__ offsets, const int* __restrict__ srcs,
    float* __restrict__ wnorm, int N) {
    int dst = (blockIdx.x * 256 + threadIdx.x) >> 6;
    if (dst >= N) return;
    int lane = threadIdx.x & 63;
    int beg = offsets[dst], end = offsets[dst + 1];
    float adv = ad_[dst];
    float denom = 0.f;
    for (int i = beg + lane; i < end; i += 64) {
        float e = as_[srcs[i]] + adv;
        e = e > 0.f ? e : NEG_SLOPE * e;
        denom += __expf(e);
    }
#pragma unroll
    for (int off = 32; off; off >>= 1) denom += __shfl_xor(denom, off, 64);
    float inv = denom > 0.f ? 1.f / denom : 0.f;
    for (int i = beg + lane; i < end; i += 64) {
        float e = as_[srcs[i]] + adv;
        e = e > 0.f ? e : NEG_SLOPE * e;
        wnorm[i] = __expf(e) * inv;
    }
}

// ---------------------------------------------------------------------------
// Pure weighted gather, one wave per (dst, plane). No exp / as_ / denom here.
// 8 edge slots x 8 feat lanes, 8B plane-row loads, 4-deep unroll.
__global__ __launch_bounds__(256) void gat_gather(
    const unsigned short* __restrict__ hb, const float* __restrict__ wnorm,
    const int* __restrict__ offsets, const int* __restrict__ srcs,
    const float* __restrict__ bvec, const float* __restrict__ x0,
    float* __restrict__ xout, int N) {
    int b = blockIdx.x;
    int plane = (b >> 2) & 1;              // b&7: 0-3 -> plane 0, 4-7 -> plane 1
    int w = (b >> 3) * 4 + (b & 3);
    int dst = w * 4 + (threadIdx.x >> 6);
    if (dst >= N) return;
    int lane = threadIdx.x & 63;
    int eslot = lane >> 3;   // edge slot 0..7
    int q = lane & 7;        // feature quad 0..7
    int beg = offsets[dst], end = offsets[dst + 1];

    f32x4 acc = {0.f, 0.f, 0.f, 0.f};
    const unsigned short* hq = hb + (size_t)plane * N * 32 + (q << 2);

#define SLOT(J)                                                              \
    {                                                                        \
        int j_ = (J);                                                        \
        float wj = __shfl(wv, j_, 64);                                       \
        int sj = __shfl(s, j_, 64);                                          \
        ushort4 hv = *(const ushort4*)(hq + (sj << 5));                      \
        acc.x = fmaf(wj, bf2f(hv.x), acc.x);                                 \
        acc.y = fmaf(wj, bf2f(hv.y), acc.y);                                 \
        acc.z = fmaf(wj, bf2f(hv.z), acc.z);                                 \
        acc.w = fmaf(wj, bf2f(hv.w), acc.w);                                 \
    }

    for (int cbeg = beg; cbeg < end; cbeg += 64) {
        int i = cbeg + lane;
        float wv = 0.f;
        int s = 0;
        if (i < end) {
            s = srcs[i];
            wv = wnorm[i];
        }
        int cnt = min(64, end - cbeg);
        int njj = (cnt + 7) >> 3;
        int jj = 0;
        for (; jj + 4 <= njj; jj += 4) {
            int j0 = (jj << 3) | eslot;
            SLOT(j0); SLOT(j0 + 8); SLOT(j0 + 16); SLOT(j0 + 24);
        }
        for (; jj < njj; jj++) {
            SLOT((jj << 3) | eslot);
        }
    }
#undef SLOT

#pragma unroll
    for (int off = 8; off <= 32; off <<= 1) {
        acc.x += __shfl_xor(acc.x, off, 64);
        acc.y += __shfl_xor(acc.y, off, 64);
        acc.z += __shfl_xor(acc.z, off, 64);
        acc.w += __shfl_xor(acc.w, off, 64);
    }
    if (eslot == 0) {
        int fbase = plane * 32 + (q << 2);
        f32x4 b4 = *(const f32x4*)(bvec + fbase);
        f32x4 xv = *(const f32x4*)(x0 + (size_t)dst * FDIM + fbase);
        f32x4 o;
        o.x = BETA * (acc.x + b4.x) + (1.f - BETA) * xv.x;
        o.y = BETA * (acc.y + b4.y) + (1.f - BETA) * xv.y;
        o.z = BETA * (acc.z + b4.z) + (1.f - BETA) * xv.z;
        o.w = BETA * (acc.w + b4.w) + (1.f - BETA) * xv.w;
        *(f32x4*)(xout + (size_t)dst * FDIM + fbase) = o;
    }
}

// ---------------------------------------------------------------------------
extern "C" void kernel_launch(void* const* d_in, const int* in_sizes, int n_in,
                              void* d_out, int out_size, void* d_ws, size_t ws_size,
                              hipStream_t stream) {
    const int N = N_NODES;
    const int E = in_sizes[1] / 2;
    const int NB = (N + 255) >> 8;   // 196 buckets

    const float* x     = (const float*)d_in[0];
    const void*  ei    = d_in[1];
    const float* W     = (const float*)d_in[2];
    const float* a_src = (const float*)d_in[3];
    const float* a_dst = (const float*)d_in[4];
    const float* bvec  = (const float*)d_in[5];
    const float* fc_w  = (const float*)d_in[6];
    const float* fc_b  = (const float*)d_in[7];

    float* out = (float*)d_out;                 // [N, F]
    float* x3  = out + (size_t)N * FDIM;        // [N, F] (second output = h)

    char* p = (char*)d_ws;
    auto alloc = [&](size_t bytes) -> void* {
        void* r = (void*)p;
        p += (bytes + 255) & ~(size_t)255;
        return r;
    };
    int*            bCounts  = (int*)alloc(512 * 4);   // counts[256] + gCursor[256]
    unsigned int*   pairs    = (unsigned int*)alloc((size_t)E * 4);
    int*            srcs     = (int*)alloc((size_t)E * 4);
    float*          wnorm    = (float*)alloc((size_t)E * 4);
    int*            offsets  = (int*)alloc((size_t)(N + 1) * 4);
    float*          as_      = (float*)alloc((size_t)N * 4);
    float*          ad_      = (float*)alloc((size_t)N * 4);
    unsigned short* hbuf     = (unsigned short*)alloc((size_t)N * FDIM * 2);
    float*          xbuf     = (float*)alloc((size_t)N * FDIM * 4);
    unsigned short* WTh      = (unsigned short*)alloc(4096 * 2);
    unsigned short* WTl      = (unsigned short*)alloc(4096 * 2);
    unsigned short* FTh      = (unsigned short*)alloc(4096 * 2);
    unsigned short* FTl      = (unsigned short*)alloc(4096 * 2);
    int* gCursor = bCounts + 256;

    hipMemsetAsync(bCounts, 0, 512 * 4, stream);

    prep_weights<<<16, 256, 0, stream>>>(W, fc_w, WTh, WTl, FTh, FTl);

    hist_kernel<<<512, 256, 0, stream>>>((const unsigned int*)ei, (const int*)ei,
                                         (const long long*)ei, bCounts, E);
    scatter_pairs<<<(E + CHUNK - 1) / CHUNK, 256, 0, stream>>>(
        (const unsigned int*)ei, (const int*)ei, (const long long*)ei,
        bCounts, gCursor, pairs, E);
    bucket_sort<<<NB, 256, 0, stream>>>(pairs, bCounts, offsets, srcs, N, E);

    int tgrid = (N + 63) / 64;
    int wgrid = (N * 64 + 255) / 256;
    int ggrid = 2 * ((N + 3) / 4);   // 2 planes x dst-waves, 4 dst/block

    // layer 1
    transform_mfma<<<tgrid, 256, 0, stream>>>(x, WTh, WTl, a_src, a_dst, nullptr,
                                              hbuf, nullptr, as_, ad_, N);
    edge_weights<<<wgrid, 256, 0, stream>>>(as_, ad_, offsets, srcs, wnorm, N);
    gat_gather<<<ggrid, 256, 0, stream>>>(hbuf, wnorm, offsets, srcs, bvec, x, xbuf, N);
    // layer 2
    transform_mfma<<<tgrid, 256, 0, stream>>>(xbuf, WTh, WTl, a_src, a_dst, nullptr,
                                              hbuf, nullptr, as_, ad_, N);
    edge_weights<<<wgrid, 256, 0, stream>>>(as_, ad_, offsets, srcs, wnorm, N);
    gat_gather<<<ggrid, 256, 0, stream>>>(hbuf, wnorm, offsets, srcs, bvec, x, xbuf, N);
    // layer 3
    transform_mfma<<<tgrid, 256, 0, stream>>>(xbuf, WTh, WTl, a_src, a_dst, nullptr,
                                              hbuf, nullptr, as_, ad_, N);
    edge_weights<<<wgrid, 256, 0, stream>>>(as_, ad_, offsets, srcs, wnorm, N);
    gat_gather<<<ggrid, 256, 0, stream>>>(hbuf, wnorm, offsets, srcs, bvec, x, x3, N);
    // final fc: out = x3 @ fc_w + fc_b
    transform_mfma<<<tgrid, 256, 0, stream>>>(x3, FTh, FTl, nullptr, nullptr, fc_b,
                                              nullptr, out, nullptr, nullptr, N);
}

// Round 10
// 279.651 us; speedup vs baseline: 1.2594x; 1.2365x over previous
//
#include <hip/hip_runtime.h>
#include <hip/hip_bf16.h>
#include <math.h>

#define N_NODES 50000
#define FDIM 64
#define BETA 0.5f
#define NEG_SLOPE 0.2f

typedef __attribute__((ext_vector_type(8))) short bf16x8;
typedef __attribute__((ext_vector_type(4))) float f32x4;

__device__ __forceinline__ unsigned short f2bf(float f) {
    unsigned u = __float_as_uint(f);
    unsigned r = (u + 0x7FFFu + ((u >> 16) & 1u)) >> 16;
    return (unsigned short)r;
}
__device__ __forceinline__ float bf2f(unsigned short s) {
    return __uint_as_float((unsigned)s << 16);
}

// ---------------------------------------------------------------------------
// Histogram of dst buckets (bucket = dst>>8) with per-block int64/int32
// self-detection (odd dwords of int64 data are all zero since N < 2^31).
__global__ __launch_bounds__(256) void hist_kernel(
    const unsigned int* __restrict__ eiu, const int* __restrict__ ei32,
    const long long* __restrict__ ei64, int* __restrict__ bucketCounts, int E) {
    __shared__ int det;
    __shared__ int h[256];
    int t = threadIdx.x;
    if (t == 0) det = 0;
    h[t] = 0;
    __syncthreads();
    unsigned base = blockIdx.x * 256 + t;
    if (base < (unsigned)E && eiu[2 * base + 1] != 0u) atomicOr(&det, 1);
    __syncthreads();
    bool is32 = det != 0;
    for (int i = blockIdx.x * blockDim.x + t; i < E; i += gridDim.x * blockDim.x) {
        int d = is32 ? ei32[E + i] : (int)ei64[E + i];
        atomicAdd(&h[d >> 8], 1);
    }
    __syncthreads();
    if (h[t]) atomicAdd(&bucketCounts[t], h[t]);
}

// Block-aggregated scatter of packed (src | dlow<<16) into bucket regions.
#define CHUNK 4096
__global__ __launch_bounds__(256) void scatter_pairs(
    const unsigned int* __restrict__ eiu, const int* __restrict__ ei32,
    const long long* __restrict__ ei64, const int* __restrict__ bucketCounts,
    int* __restrict__ gCursor, unsigned int* __restrict__ pairs, int E) {
    __shared__ int det;
    __shared__ int sc[256], hist[256], base[256], cur[256];
    int t = threadIdx.x;
    if (t == 0) det = 0;
    hist[t] = 0; cur[t] = 0;
    __syncthreads();
    int beg = blockIdx.x * CHUNK;
    int end = min(E, beg + CHUNK);
    {
        int idx = beg + t;
        if (idx < E && eiu[2 * idx + 1] != 0u) atomicOr(&det, 1);
    }
    int c = bucketCounts[t];
    sc[t] = c;
    __syncthreads();
    bool is32 = det != 0;
    for (int off = 1; off < 256; off <<= 1) {
        int v = (t >= off) ? sc[t - off] : 0;
        __syncthreads();
        sc[t] += v;
        __syncthreads();
    }
    int bucketExcl = sc[t] - c;
    for (int i = beg + t; i < end; i += 256) {
        int d = is32 ? ei32[E + i] : (int)ei64[E + i];
        atomicAdd(&hist[d >> 8], 1);
    }
    __syncthreads();
    if (hist[t] > 0) base[t] = bucketExcl + atomicAdd(&gCursor[t], hist[t]);
    __syncthreads();
    for (int i = beg + t; i < end; i += 256) {
        int s, d;
        if (is32) { s = ei32[i]; d = ei32[E + i]; }
        else      { s = (int)ei64[i]; d = (int)ei64[E + i]; }
        int b = d >> 8;
        int pos = base[b] + atomicAdd(&cur[b], 1);
        pairs[pos] = (unsigned int)s | ((unsigned int)(d & 255) << 16);
    }
}

// One block per bucket: counting sort by full dst; writes per-node offsets + srcs.
__global__ __launch_bounds__(256) void bucket_sort(
    const unsigned int* __restrict__ pairs, const int* __restrict__ bucketCounts,
    int* __restrict__ offsets, int* __restrict__ srcs, int N, int E) {
    __shared__ int scb[256], cnt[256], sc[256], cur[256];
    int b = blockIdx.x, t = threadIdx.x;
    int cb = bucketCounts[t];
    scb[t] = cb;
    __syncthreads();
    for (int off = 1; off < 256; off <<= 1) {
        int v = (t >= off) ? scb[t - off] : 0;
        __syncthreads();
        scb[t] += v;
        __syncthreads();
    }
    int beg = scb[b] - bucketCounts[b];
    int end = scb[b];
    if (b == 0 && t == 0) offsets[N] = E;
    cnt[t] = 0;
    __syncthreads();
    for (int i = beg + t; i < end; i += 256) atomicAdd(&cnt[(pairs[i] >> 16) & 255u], 1);
    __syncthreads();
    sc[t] = cnt[t];
    __syncthreads();
    for (int off = 1; off < 256; off <<= 1) {
        int v = (t >= off) ? sc[t - off] : 0;
        __syncthreads();
        sc[t] += v;
        __syncthreads();
    }
    int excl = sc[t] - cnt[t];
    int node = (b << 8) + t;
    if (node < N) offsets[node] = beg + excl;
    cur[t] = beg + excl;
    __syncthreads();
    for (int i = beg + t; i < end; i += 256) {
        unsigned int p = pairs[i];
        int pos = atomicAdd(&cur[(p >> 16) & 255u], 1);
        srcs[pos] = (int)(p & 0xFFFFu);
    }
}

// ---------------------------------------------------------------------------
// Prep: transpose W and fc_w into bf16 hi/lo, WT[f*64+k] = split(W[k*64+f]).
__global__ __launch_bounds__(256) void prep_weights(
    const float* __restrict__ W, const float* __restrict__ fcw,
    unsigned short* __restrict__ WTh, unsigned short* __restrict__ WTl,
    unsigned short* __restrict__ FTh, unsigned short* __restrict__ FTl) {
    for (int idx = blockIdx.x * 256 + threadIdx.x; idx < 4096; idx += gridDim.x * 256) {
        int k = idx >> 6, f = idx & 63;
        float w = W[idx];
        unsigned short hi = f2bf(w);
        WTh[f * 64 + k] = hi;
        WTl[f * 64 + k] = f2bf(w - bf2f(hi));
        float w2 = fcw[idx];
        unsigned short hi2 = f2bf(w2);
        FTh[f * 64 + k] = hi2;
        FTl[f * 64 + k] = f2bf(w2 - bf2f(hi2));
    }
}

// ---------------------------------------------------------------------------
// Split-bf16 MFMA transform: h = x@W (fp32-accurate via xh*Wh + xh*Wl + xl*Wh).
// hb written CONTIGUOUS: hb[node*64 + f] (plane-split measured slower, R8/R9).
__global__ __launch_bounds__(256, 4) void transform_mfma(
    const float* __restrict__ x,
    const unsigned short* __restrict__ WTh, const unsigned short* __restrict__ WTl,
    const float* __restrict__ a_src, const float* __restrict__ a_dst,  // nullable
    const float* __restrict__ bias,                                    // nullable
    unsigned short* __restrict__ hb,  // bf16 out (layers), nullable
    float* __restrict__ fout,         // fp32 out (FC), nullable
    float* __restrict__ as_, float* __restrict__ ad_, int N) {
    __shared__ __align__(16) unsigned short WThs[64 * 72];
    __shared__ __align__(16) unsigned short WTls[64 * 72];
    int tid = threadIdx.x;
    {
        int row = tid >> 2;            // 0..63
        int ch = (tid & 3) * 16;       // shorts
        uint4 h0 = ((const uint4*)(WTh + row * 64 + ch))[0];
        uint4 h1 = ((const uint4*)(WTh + row * 64 + ch))[1];
        uint4 l0 = ((const uint4*)(WTl + row * 64 + ch))[0];
        uint4 l1 = ((const uint4*)(WTl + row * 64 + ch))[1];
        *((uint4*)(WThs + row * 72 + ch)) = h0;
        *((uint4*)(WThs + row * 72 + ch + 8)) = h1;
        *((uint4*)(WTls + row * 72 + ch)) = l0;
        *((uint4*)(WTls + row * 72 + ch + 8)) = l1;
    }

    int wid = tid >> 6;
    int lane = tid & 63;
    int col = lane & 15;
    int quad = lane >> 4;
    int mbase = blockIdx.x * 64 + wid * 16;

    bf16x8 Ah[2], Al[2];
    int arow = mbase + col;
    const float* xr = x + (size_t)(arow < N ? arow : 0) * FDIM + quad * 8;
#pragma unroll
    for (int ks = 0; ks < 2; ks++) {
        float4 xa = *(const float4*)(xr + ks * 32);
        float4 xb = *(const float4*)(xr + ks * 32 + 4);
        float xv[8] = {xa.x, xa.y, xa.z, xa.w, xb.x, xb.y, xb.z, xb.w};
#pragma unroll
        for (int e = 0; e < 8; e++) {
            unsigned short hi = f2bf(xv[e]);
            Ah[ks][e] = (short)hi;
            Al[ks][e] = (short)f2bf(xv[e] - bf2f(hi));
        }
    }
    __syncthreads();

    f32x4 acc[4];
#pragma unroll
    for (int ft = 0; ft < 4; ft++) acc[ft] = (f32x4){0.f, 0.f, 0.f, 0.f};

#pragma unroll
    for (int ft = 0; ft < 4; ft++) {
        int f = ft * 16 + col;
#pragma unroll
        for (int ks = 0; ks < 2; ks++) {
            int off = f * 72 + ks * 32 + quad * 8;
            bf16x8 Bh = *(const bf16x8*)(WThs + off);
            bf16x8 Bl = *(const bf16x8*)(WTls + off);
            acc[ft] = __builtin_amdgcn_mfma_f32_16x16x32_bf16(Ah[ks], Bh, acc[ft], 0, 0, 0);
            acc[ft] = __builtin_amdgcn_mfma_f32_16x16x32_bf16(Ah[ks], Bl, acc[ft], 0, 0, 0);
            acc[ft] = __builtin_amdgcn_mfma_f32_16x16x32_bf16(Al[ks], Bh, acc[ft], 0, 0, 0);
        }
    }

    if (fout) {
#pragma unroll
        for (int ft = 0; ft < 4; ft++) {
            int f = ft * 16 + col;
            float bv = bias ? bias[f] : 0.f;
#pragma unroll
            for (int r = 0; r < 4; r++) {
                int node = mbase + quad * 4 + r;
                if (node < N) fout[(size_t)node * FDIM + f] = acc[ft][r] + bv;
            }
        }
    }
    if (hb) {
#pragma unroll
        for (int ft = 0; ft < 4; ft++) {
            int f = ft * 16 + col;
#pragma unroll
            for (int r = 0; r < 4; r++) {
                int node = mbase + quad * 4 + r;
                if (node < N) hb[(size_t)node * FDIM + f] = f2bf(acc[ft][r]);
            }
        }
    }
    if (as_) {
        float asv[4], adv[4];
#pragma unroll
        for (int ft = 0; ft < 4; ft++) {
            asv[ft] = a_src[ft * 16 + col];
            adv[ft] = a_dst[ft * 16 + col];
        }
#pragma unroll
        for (int r = 0; r < 4; r++) {
            float pa = 0.f, pd = 0.f;
#pragma unroll
            for (int ft = 0; ft < 4; ft++) {
                pa = fmaf(acc[ft][r], asv[ft], pa);
                pd = fmaf(acc[ft][r], adv[ft], pd);
            }
#pragma unroll
            for (int off = 1; off <= 8; off <<= 1) {
                pa += __shfl_xor(pa, off, 64);
                pd += __shfl_xor(pd, off, 64);
            }
            int node = mbase + quad * 4 + r;
            if (col == 0 && node < N) { as_[node] = pa; ad_[node] = pd; }
        }
    }
}

// ---------------------------------------------------------------------------
// One wave per dst node, single pass fused softmax (logits bounded, fp32 exp
// safe). 4 edge slots x 16 feat lanes, bf16 ushort4 h-row loads, 4-deep unroll.
// (R6-measured best structure; plane-split variants regressed — R8/R9.)
__global__ __launch_bounds__(256) void gat_gather(
    const unsigned short* __restrict__ hb,
    const float* __restrict__ as_, const float* __restrict__ ad_,
    const int* __restrict__ offsets, const int* __restrict__ srcs,
    const float* __restrict__ bvec, const float* __restrict__ x0,
    float* __restrict__ xout, int N) {
    int wid = (blockIdx.x * blockDim.x + threadIdx.x) >> 6;
    if (wid >= N) return;
    int lane = threadIdx.x & 63;
    int g = lane >> 4;      // edge slot 0..3
    int q = lane & 15;      // feature quad 0..15
    int beg = offsets[wid], end = offsets[wid + 1];
    float adv = ad_[wid];

    f32x4 acc = {0.f, 0.f, 0.f, 0.f};
    float denom = 0.f;
    const unsigned short* hq = hb + (q << 2);

#define SLOT(J)                                                              \
    {                                                                        \
        int j_ = (J);                                                        \
        float exj = __shfl(ex, j_, 64);                                      \
        int sj = __shfl(s, j_, 64);                                          \
        ushort4 hv = *(const ushort4*)(hq + (size_t)sj * FDIM);              \
        acc.x = fmaf(exj, bf2f(hv.x), acc.x);                                \
        acc.y = fmaf(exj, bf2f(hv.y), acc.y);                                \
        acc.z = fmaf(exj, bf2f(hv.z), acc.z);                                \
        acc.w = fmaf(exj, bf2f(hv.w), acc.w);                                \
    }

    for (int cbeg = beg; cbeg < end; cbeg += 64) {
        int i = cbeg + lane;
        float ex = 0.f;
        int s = 0;
        if (i < end) {
            s = srcs[i];
            float e = as_[s] + adv;
            e = e > 0.f ? e : NEG_SLOPE * e;
            ex = __expf(e);
        }
        denom += ex;
        int cnt = min(64, end - cbeg);
        int njj = (cnt + 3) >> 2;
        int jj = 0;
        for (; jj + 4 <= njj; jj += 4) {
            int j0 = (jj << 2) | g;
            SLOT(j0); SLOT(j0 + 4); SLOT(j0 + 8); SLOT(j0 + 12);
        }
        for (; jj < njj; jj++) {
            SLOT((jj << 2) | g);
        }
    }
#undef SLOT

#pragma unroll
    for (int off = 32; off; off >>= 1) denom += __shfl_xor(denom, off, 64);
#pragma unroll
    for (int off = 16; off <= 32; off <<= 1) {
        acc.x += __shfl_xor(acc.x, off, 64);
        acc.y += __shfl_xor(acc.y, off, 64);
        acc.z += __shfl_xor(acc.z, off, 64);
        acc.w += __shfl_xor(acc.w, off, 64);
    }
    if (g == 0) {
        float inv = denom > 0.f ? 1.f / denom : 0.f;
        f32x4 b4 = *(const f32x4*)(bvec + (q << 2));
        f32x4 xv = *(const f32x4*)(x0 + (size_t)wid * FDIM + (q << 2));
        f32x4 o;
        o.x = BETA * (acc.x * inv + b4.x) + (1.f - BETA) * xv.x;
        o.y = BETA * (acc.y * inv + b4.y) + (1.f - BETA) * xv.y;
        o.z = BETA * (acc.z * inv + b4.z) + (1.f - BETA) * xv.z;
        o.w = BETA * (acc.w * inv + b4.w) + (1.f - BETA) * xv.w;
        *(f32x4*)(xout + (size_t)wid * FDIM + (q << 2)) = o;
    }
}

// ---------------------------------------------------------------------------
extern "C" void kernel_launch(void* const* d_in, const int* in_sizes, int n_in,
                              void* d_out, int out_size, void* d_ws, size_t ws_size,
                              hipStream_t stream) {
    const int N = N_NODES;
    const int E = in_sizes[1] / 2;
    const int NB = (N + 255) >> 8;   // 196 buckets

    const float* x     = (const float*)d_in[0];
    const void*  ei    = d_in[1];
    const float* W     = (const float*)d_in[2];
    const float* a_src = (const float*)d_in[3];
    const float* a_dst = (const float*)d_in[4];
    const float* bvec  = (const float*)d_in[5];
    const float* fc_w  = (const float*)d_in[6];
    const float* fc_b  = (const float*)d_in[7];

    float* out = (float*)d_out;                 // [N, F]
    float* x3  = out + (size_t)N * FDIM;        // [N, F] (second output = h)

    char* p = (char*)d_ws;
    auto alloc = [&](size_t bytes) -> void* {
        void* r = (void*)p;
        p += (bytes + 255) & ~(size_t)255;
        return r;
    };
    int*            bCounts  = (int*)alloc(512 * 4);   // counts[256] + gCursor[256]
    unsigned int*   pairs    = (unsigned int*)alloc((size_t)E * 4);
    int*            srcs     = (int*)alloc((size_t)E * 4);
    int*            offsets  = (int*)alloc((size_t)(N + 1) * 4);
    float*          as_      = (float*)alloc((size_t)N * 4);
    float*          ad_      = (float*)alloc((size_t)N * 4);
    unsigned short* hbuf     = (unsigned short*)alloc((size_t)N * FDIM * 2);
    float*          xbuf     = (float*)alloc((size_t)N * FDIM * 4);
    unsigned short* WTh      = (unsigned short*)alloc(4096 * 2);
    unsigned short* WTl      = (unsigned short*)alloc(4096 * 2);
    unsigned short* FTh      = (unsigned short*)alloc(4096 * 2);
    unsigned short* FTl      = (unsigned short*)alloc(4096 * 2);
    int* gCursor = bCounts + 256;

    hipMemsetAsync(bCounts, 0, 512 * 4, stream);

    prep_weights<<<16, 256, 0, stream>>>(W, fc_w, WTh, WTl, FTh, FTl);

    hist_kernel<<<512, 256, 0, stream>>>((const unsigned int*)ei, (const int*)ei,
                                         (const long long*)ei, bCounts, E);
    scatter_pairs<<<(E + CHUNK - 1) / CHUNK, 256, 0, stream>>>(
        (const unsigned int*)ei, (const int*)ei, (const long long*)ei,
        bCounts, gCursor, pairs, E);
    bucket_sort<<<NB, 256, 0, stream>>>(pairs, bCounts, offsets, srcs, N, E);

    int tgrid = (N + 63) / 64;
    int ggrid = (N * 64 + 255) / 256;

    // layer 1
    transform_mfma<<<tgrid, 256, 0, stream>>>(x, WTh, WTl, a_src, a_dst, nullptr,
                                              hbuf, nullptr, as_, ad_, N);
    gat_gather<<<ggrid, 256, 0, stream>>>(hbuf, as_, ad_, offsets, srcs, bvec, x, xbuf, N);
    // layer 2
    transform_mfma<<<tgrid, 256, 0, stream>>>(xbuf, WTh, WTl, a_src, a_dst, nullptr,
                                              hbuf, nullptr, as_, ad_, N);
    gat_gather<<<ggrid, 256, 0, stream>>>(hbuf, as_, ad_, offsets, srcs, bvec, x, xbuf, N);
    // layer 3
    transform_mfma<<<tgrid, 256, 0, stream>>>(xbuf, WTh, WTl, a_src, a_dst, nullptr,
                                              hbuf, nullptr, as_, ad_, N);
    gat_gather<<<ggrid, 256, 0, stream>>>(hbuf, as_, ad_, offsets, srcs, bvec, x, x3, N);
    // final fc: out = x3 @ fc_w + fc_b
    transform_mfma<<<tgrid, 256, 0, stream>>>(x3, FTh, FTl, nullptr, nullptr, fc_b,
                                              nullptr, out, nullptr, nullptr, N);
}

// Round 11
// 274.874 us; speedup vs baseline: 1.2813x; 1.0174x over previous
//
#include <hip/hip_runtime.h>
#include <hip/hip_bf16.h>
#include <math.h>

#define N_NODES 50000
#define FDIM 64
#define BETA 0.5f
#define NEG_SLOPE 0.2f

typedef __attribute__((ext_vector_type(8))) short bf16x8;
typedef __attribute__((ext_vector_type(4))) float f32x4;

__device__ __forceinline__ unsigned short f2bf(float f) {
    unsigned u = __float_as_uint(f);
    unsigned r = (u + 0x7FFFu + ((u >> 16) & 1u)) >> 16;
    return (unsigned short)r;
}
__device__ __forceinline__ float bf2f(unsigned short s) {
    return __uint_as_float((unsigned)s << 16);
}

// ---------------------------------------------------------------------------
// Histogram of dst buckets (bucket = dst>>8) with per-block int64/int32
// self-detection (odd dwords of int64 data are all zero since N < 2^31).
__global__ __launch_bounds__(256) void hist_kernel(
    const unsigned int* __restrict__ eiu, const int* __restrict__ ei32,
    const long long* __restrict__ ei64, int* __restrict__ bucketCounts, int E) {
    __shared__ int det;
    __shared__ int h[256];
    int t = threadIdx.x;
    if (t == 0) det = 0;
    h[t] = 0;
    __syncthreads();
    unsigned base = blockIdx.x * 256 + t;
    if (base < (unsigned)E && eiu[2 * base + 1] != 0u) atomicOr(&det, 1);
    __syncthreads();
    bool is32 = det != 0;
    for (int i = blockIdx.x * blockDim.x + t; i < E; i += gridDim.x * blockDim.x) {
        int d = is32 ? ei32[E + i] : (int)ei64[E + i];
        atomicAdd(&h[d >> 8], 1);
    }
    __syncthreads();
    if (h[t]) atomicAdd(&bucketCounts[t], h[t]);
}

// Block-aggregated scatter of packed (src | dlow<<16) into bucket regions.
#define CHUNK 4096
__global__ __launch_bounds__(256) void scatter_pairs(
    const unsigned int* __restrict__ eiu, const int* __restrict__ ei32,
    const long long* __restrict__ ei64, const int* __restrict__ bucketCounts,
    int* __restrict__ gCursor, unsigned int* __restrict__ pairs, int E) {
    __shared__ int det;
    __shared__ int sc[256], hist[256], base[256], cur[256];
    int t = threadIdx.x;
    if (t == 0) det = 0;
    hist[t] = 0; cur[t] = 0;
    __syncthreads();
    int beg = blockIdx.x * CHUNK;
    int end = min(E, beg + CHUNK);
    {
        int idx = beg + t;
        if (idx < E && eiu[2 * idx + 1] != 0u) atomicOr(&det, 1);
    }
    int c = bucketCounts[t];
    sc[t] = c;
    __syncthreads();
    bool is32 = det != 0;
    for (int off = 1; off < 256; off <<= 1) {
        int v = (t >= off) ? sc[t - off] : 0;
        __syncthreads();
        sc[t] += v;
        __syncthreads();
    }
    int bucketExcl = sc[t] - c;
    for (int i = beg + t; i < end; i += 256) {
        int d = is32 ? ei32[E + i] : (int)ei64[E + i];
        atomicAdd(&hist[d >> 8], 1);
    }
    __syncthreads();
    if (hist[t] > 0) base[t] = bucketExcl + atomicAdd(&gCursor[t], hist[t]);
    __syncthreads();
    for (int i = beg + t; i < end; i += 256) {
        int s, d;
        if (is32) { s = ei32[i]; d = ei32[E + i]; }
        else      { s = (int)ei64[i]; d = (int)ei64[E + i]; }
        int b = d >> 8;
        int pos = base[b] + atomicAdd(&cur[b], 1);
        pairs[pos] = (unsigned int)s | ((unsigned int)(d & 255) << 16);
    }
}

// One block per bucket: counting sort by full dst; writes per-node offsets + srcs.
__global__ __launch_bounds__(256) void bucket_sort(
    const unsigned int* __restrict__ pairs, const int* __restrict__ bucketCounts,
    int* __restrict__ offsets, int* __restrict__ srcs, int N, int E) {
    __shared__ int scb[256], cnt[256], sc[256], cur[256];
    int b = blockIdx.x, t = threadIdx.x;
    int cb = bucketCounts[t];
    scb[t] = cb;
    __syncthreads();
    for (int off = 1; off < 256; off <<= 1) {
        int v = (t >= off) ? scb[t - off] : 0;
        __syncthreads();
        scb[t] += v;
        __syncthreads();
    }
    int beg = scb[b] - bucketCounts[b];
    int end = scb[b];
    if (b == 0 && t == 0) offsets[N] = E;
    cnt[t] = 0;
    __syncthreads();
    for (int i = beg + t; i < end; i += 256) atomicAdd(&cnt[(pairs[i] >> 16) & 255u], 1);
    __syncthreads();
    sc[t] = cnt[t];
    __syncthreads();
    for (int off = 1; off < 256; off <<= 1) {
        int v = (t >= off) ? sc[t - off] : 0;
        __syncthreads();
        sc[t] += v;
        __syncthreads();
    }
    int excl = sc[t] - cnt[t];
    int node = (b << 8) + t;
    if (node < N) offsets[node] = beg + excl;
    cur[t] = beg + excl;
    __syncthreads();
    for (int i = beg + t; i < end; i += 256) {
        unsigned int p = pairs[i];
        int pos = atomicAdd(&cur[(p >> 16) & 255u], 1);
        srcs[pos] = (int)(p & 0xFFFFu);
    }
}

// ---------------------------------------------------------------------------
// Prep: transpose W and fc_w into bf16 hi/lo, WT[f*64+k] = split(W[k*64+f]).
__global__ __launch_bounds__(256) void prep_weights(
    const float* __restrict__ W, const float* __restrict__ fcw,
    unsigned short* __restrict__ WTh, unsigned short* __restrict__ WTl,
    unsigned short* __restrict__ FTh, unsigned short* __restrict__ FTl) {
    for (int idx = blockIdx.x * 256 + threadIdx.x; idx < 4096; idx += gridDim.x * 256) {
        int k = idx >> 6, f = idx & 63;
        float w = W[idx];
        unsigned short hi = f2bf(w);
        WTh[f * 64 + k] = hi;
        WTl[f * 64 + k] = f2bf(w - bf2f(hi));
        float w2 = fcw[idx];
        unsigned short hi2 = f2bf(w2);
        FTh[f * 64 + k] = hi2;
        FTl[f * 64 + k] = f2bf(w2 - bf2f(hi2));
    }
}

// ---------------------------------------------------------------------------
// Split-bf16 MFMA transform: h = x@W (fp32-accurate via xh*Wh + xh*Wl + xl*Wh).
// hb written CONTIGUOUS: hb[node*64 + f].
__global__ __launch_bounds__(256, 4) void transform_mfma(
    const float* __restrict__ x,
    const unsigned short* __restrict__ WTh, const unsigned short* __restrict__ WTl,
    const float* __restrict__ a_src, const float* __restrict__ a_dst,  // nullable
    const float* __restrict__ bias,                                    // nullable
    unsigned short* __restrict__ hb,  // bf16 out (layers), nullable
    float* __restrict__ fout,         // fp32 out (FC), nullable
    float* __restrict__ as_, float* __restrict__ ad_, int N) {
    __shared__ __align__(16) unsigned short WThs[64 * 72];
    __shared__ __align__(16) unsigned short WTls[64 * 72];
    int tid = threadIdx.x;
    {
        int row = tid >> 2;            // 0..63
        int ch = (tid & 3) * 16;       // shorts
        uint4 h0 = ((const uint4*)(WTh + row * 64 + ch))[0];
        uint4 h1 = ((const uint4*)(WTh + row * 64 + ch))[1];
        uint4 l0 = ((const uint4*)(WTl + row * 64 + ch))[0];
        uint4 l1 = ((const uint4*)(WTl + row * 64 + ch))[1];
        *((uint4*)(WThs + row * 72 + ch)) = h0;
        *((uint4*)(WThs + row * 72 + ch + 8)) = h1;
        *((uint4*)(WTls + row * 72 + ch)) = l0;
        *((uint4*)(WTls + row * 72 + ch + 8)) = l1;
    }

    int wid = tid >> 6;
    int lane = tid & 63;
    int col = lane & 15;
    int quad = lane >> 4;
    int mbase = blockIdx.x * 64 + wid * 16;

    bf16x8 Ah[2], Al[2];
    int arow = mbase + col;
    const float* xr = x + (size_t)(arow < N ? arow : 0) * FDIM + quad * 8;
#pragma unroll
    for (int ks = 0; ks < 2; ks++) {
        float4 xa = *(const float4*)(xr + ks * 32);
        float4 xb = *(const float4*)(xr + ks * 32 + 4);
        float xv[8] = {xa.x, xa.y, xa.z, xa.w, xb.x, xb.y, xb.z, xb.w};
#pragma unroll
        for (int e = 0; e < 8; e++) {
            unsigned short hi = f2bf(xv[e]);
            Ah[ks][e] = (short)hi;
            Al[ks][e] = (short)f2bf(xv[e] - bf2f(hi));
        }
    }
    __syncthreads();

    f32x4 acc[4];
#pragma unroll
    for (int ft = 0; ft < 4; ft++) acc[ft] = (f32x4){0.f, 0.f, 0.f, 0.f};

#pragma unroll
    for (int ft = 0; ft < 4; ft++) {
        int f = ft * 16 + col;
#pragma unroll
        for (int ks = 0; ks < 2; ks++) {
            int off = f * 72 + ks * 32 + quad * 8;
            bf16x8 Bh = *(const bf16x8*)(WThs + off);
            bf16x8 Bl = *(const bf16x8*)(WTls + off);
            acc[ft] = __builtin_amdgcn_mfma_f32_16x16x32_bf16(Ah[ks], Bh, acc[ft], 0, 0, 0);
            acc[ft] = __builtin_amdgcn_mfma_f32_16x16x32_bf16(Ah[ks], Bl, acc[ft], 0, 0, 0);
            acc[ft] = __builtin_amdgcn_mfma_f32_16x16x32_bf16(Al[ks], Bh, acc[ft], 0, 0, 0);
        }
    }

    if (fout) {
#pragma unroll
        for (int ft = 0; ft < 4; ft++) {
            int f = ft * 16 + col;
            float bv = bias ? bias[f] : 0.f;
#pragma unroll
            for (int r = 0; r < 4; r++) {
                int node = mbase + quad * 4 + r;
                if (node < N) fout[(size_t)node * FDIM + f] = acc[ft][r] + bv;
            }
        }
    }
    if (hb) {
#pragma unroll
        for (int ft = 0; ft < 4; ft++) {
            int f = ft * 16 + col;
#pragma unroll
            for (int r = 0; r < 4; r++) {
                int node = mbase + quad * 4 + r;
                if (node < N) hb[(size_t)node * FDIM + f] = f2bf(acc[ft][r]);
            }
        }
    }
    if (as_) {
        float asv[4], adv[4];
#pragma unroll
        for (int ft = 0; ft < 4; ft++) {
            asv[ft] = a_src[ft * 16 + col];
            adv[ft] = a_dst[ft * 16 + col];
        }
#pragma unroll
        for (int r = 0; r < 4; r++) {
            float pa = 0.f, pd = 0.f;
#pragma unroll
            for (int ft = 0; ft < 4; ft++) {
                pa = fmaf(acc[ft][r], asv[ft], pa);
                pd = fmaf(acc[ft][r], adv[ft], pd);
            }
#pragma unroll
            for (int off = 1; off <= 8; off <<= 1) {
                pa += __shfl_xor(pa, off, 64);
                pd += __shfl_xor(pd, off, 64);
            }
            int node = mbase + quad * 4 + r;
            if (col == 0 && node < N) { as_[node] = pa; ad_[node] = pd; }
        }
    }
}

// ---------------------------------------------------------------------------
// One wave per dst node, single-pass fused softmax (logits bounded, fp32 exp
// safe). 8 edge slots x 8 feature lanes; each SLOT: one ds_read_b64 of the
// LDS-staged (ex,src) pair + one dwordx4 (16B) row load serving 8 edges/wave.
// Wave-private LDS staging needs no barrier (same-wave DS ordering).
__global__ __launch_bounds__(256) void gat_gather(
    const unsigned short* __restrict__ hb,
    const float* __restrict__ as_, const float* __restrict__ ad_,
    const int* __restrict__ offsets, const int* __restrict__ srcs,
    const float* __restrict__ bvec, const float* __restrict__ x0,
    float* __restrict__ xout, int N) {
    __shared__ __align__(8) float2 stage[4][64];
    int wv = threadIdx.x >> 6;
    int wid = (blockIdx.x * blockDim.x + threadIdx.x) >> 6;
    if (wid >= N) return;
    int lane = threadIdx.x & 63;
    int eslot = lane >> 3;   // edge slot 0..7
    int q = lane & 7;        // feature octet 0..7 (8 bf16 each)
    int beg = offsets[wid], end = offsets[wid + 1];
    float adv = ad_[wid];

    float acc[8];
#pragma unroll
    for (int k = 0; k < 8; k++) acc[k] = 0.f;
    float denom = 0.f;
    const unsigned short* hq = hb + (q << 3);   // + q*8 shorts (16B)
    const float2* sp = &stage[wv][eslot];

#define SLOT8(P)                                                             \
    {                                                                        \
        float exj = (P).x;                                                   \
        int sj = __float_as_int((P).y);                                      \
        uint4 hv = *(const uint4*)(hq + ((size_t)sj << 6));                  \
        acc[0] = fmaf(exj, __uint_as_float(hv.x << 16), acc[0]);             \
        acc[1] = fmaf(exj, __uint_as_float(hv.x & 0xFFFF0000u), acc[1]);     \
        acc[2] = fmaf(exj, __uint_as_float(hv.y << 16), acc[2]);             \
        acc[3] = fmaf(exj, __uint_as_float(hv.y & 0xFFFF0000u), acc[3]);     \
        acc[4] = fmaf(exj, __uint_as_float(hv.z << 16), acc[4]);             \
        acc[5] = fmaf(exj, __uint_as_float(hv.z & 0xFFFF0000u), acc[5]);     \
        acc[6] = fmaf(exj, __uint_as_float(hv.w << 16), acc[6]);             \
        acc[7] = fmaf(exj, __uint_as_float(hv.w & 0xFFFF0000u), acc[7]);     \
    }

    for (int cbeg = beg; cbeg < end; cbeg += 64) {
        int i = cbeg + lane;
        float ex = 0.f;
        int s = 0;
        if (i < end) {
            s = srcs[i];
            float e = as_[s] + adv;
            e = e > 0.f ? e : NEG_SLOPE * e;
            ex = __expf(e);
        }
        denom += ex;
        stage[wv][lane] = make_float2(ex, __int_as_float(s));
        int cnt = min(64, end - cbeg);
        int njj = (cnt + 7) >> 3;
        int jj = 0;
        for (; jj + 2 <= njj; jj += 2) {
            float2 p0 = sp[jj * 8];
            float2 p1 = sp[jj * 8 + 8];
            SLOT8(p0);
            SLOT8(p1);
        }
        if (jj < njj) {
            float2 p0 = sp[jj * 8];
            SLOT8(p0);
        }
    }
#undef SLOT8

#pragma unroll
    for (int off = 1; off <= 32; off <<= 1) denom += __shfl_xor(denom, off, 64);
#pragma unroll
    for (int off = 8; off <= 32; off <<= 1) {
#pragma unroll
        for (int k = 0; k < 8; k++) acc[k] += __shfl_xor(acc[k], off, 64);
    }
    if (lane < 8) {   // lane == q, eslot == 0: owns features q*8 .. q*8+7
        float inv = denom > 0.f ? 1.f / denom : 0.f;
        int fb = lane * 8;
        f32x4 b0 = *(const f32x4*)(bvec + fb);
        f32x4 b1 = *(const f32x4*)(bvec + fb + 4);
        f32x4 x0a = *(const f32x4*)(x0 + (size_t)wid * FDIM + fb);
        f32x4 x0b = *(const f32x4*)(x0 + (size_t)wid * FDIM + fb + 4);
        f32x4 o0, o1;
        o0.x = BETA * (acc[0] * inv + b0.x) + (1.f - BETA) * x0a.x;
        o0.y = BETA * (acc[1] * inv + b0.y) + (1.f - BETA) * x0a.y;
        o0.z = BETA * (acc[2] * inv + b0.z) + (1.f - BETA) * x0a.z;
        o0.w = BETA * (acc[3] * inv + b0.w) + (1.f - BETA) * x0a.w;
        o1.x = BETA * (acc[4] * inv + b1.x) + (1.f - BETA) * x0b.x;
        o1.y = BETA * (acc[5] * inv + b1.y) + (1.f - BETA) * x0b.y;
        o1.z = BETA * (acc[6] * inv + b1.z) + (1.f - BETA) * x0b.z;
        o1.w = BETA * (acc[7] * inv + b1.w) + (1.f - BETA) * x0b.w;
        *(f32x4*)(xout + (size_t)wid * FDIM + fb) = o0;
        *(f32x4*)(xout + (size_t)wid * FDIM + fb + 4) = o1;
    }
}

// ---------------------------------------------------------------------------
extern "C" void kernel_launch(void* const* d_in, const int* in_sizes, int n_in,
                              void* d_out, int out_size, void* d_ws, size_t ws_size,
                              hipStream_t stream) {
    const int N = N_NODES;
    const int E = in_sizes[1] / 2;
    const int NB = (N + 255) >> 8;   // 196 buckets

    const float* x     = (const float*)d_in[0];
    const void*  ei    = d_in[1];
    const float* W     = (const float*)d_in[2];
    const float* a_src = (const float*)d_in[3];
    const float* a_dst = (const float*)d_in[4];
    const float* bvec  = (const float*)d_in[5];
    const float* fc_w  = (const float*)d_in[6];
    const float* fc_b  = (const float*)d_in[7];

    float* out = (float*)d_out;                 // [N, F]
    float* x3  = out + (size_t)N * FDIM;        // [N, F] (second output = h)

    char* p = (char*)d_ws;
    auto alloc = [&](size_t bytes) -> void* {
        void* r = (void*)p;
        p += (bytes + 255) & ~(size_t)255;
        return r;
    };
    int*            bCounts  = (int*)alloc(512 * 4);   // counts[256] + gCursor[256]
    unsigned int*   pairs    = (unsigned int*)alloc((size_t)E * 4);
    int*            srcs     = (int*)alloc((size_t)E * 4);
    int*            offsets  = (int*)alloc((size_t)(N + 1) * 4);
    float*          as_      = (float*)alloc((size_t)N * 4);
    float*          ad_      = (float*)alloc((size_t)N * 4);
    unsigned short* hbuf     = (unsigned short*)alloc((size_t)N * FDIM * 2);
    float*          xbuf     = (float*)alloc((size_t)N * FDIM * 4);
    unsigned short* WTh      = (unsigned short*)alloc(4096 * 2);
    unsigned short* WTl      = (unsigned short*)alloc(4096 * 2);
    unsigned short* FTh      = (unsigned short*)alloc(4096 * 2);
    unsigned short* FTl      = (unsigned short*)alloc(4096 * 2);
    int* gCursor = bCounts + 256;

    hipMemsetAsync(bCounts, 0, 512 * 4, stream);

    prep_weights<<<16, 256, 0, stream>>>(W, fc_w, WTh, WTl, FTh, FTl);

    hist_kernel<<<512, 256, 0, stream>>>((const unsigned int*)ei, (const int*)ei,
                                         (const long long*)ei, bCounts, E);
    scatter_pairs<<<(E + CHUNK - 1) / CHUNK, 256, 0, stream>>>(
        (const unsigned int*)ei, (const int*)ei, (const long long*)ei,
        bCounts, gCursor, pairs, E);
    bucket_sort<<<NB, 256, 0, stream>>>(pairs, bCounts, offsets, srcs, N, E);

    int tgrid = (N + 63) / 64;
    int ggrid = (N * 64 + 255) / 256;

    // layer 1
    transform_mfma<<<tgrid, 256, 0, stream>>>(x, WTh, WTl, a_src, a_dst, nullptr,
                                              hbuf, nullptr, as_, ad_, N);
    gat_gather<<<ggrid, 256, 0, stream>>>(hbuf, as_, ad_, offsets, srcs, bvec, x, xbuf, N);
    // layer 2
    transform_mfma<<<tgrid, 256, 0, stream>>>(xbuf, WTh, WTl, a_src, a_dst, nullptr,
                                              hbuf, nullptr, as_, ad_, N);
    gat_gather<<<ggrid, 256, 0, stream>>>(hbuf, as_, ad_, offsets, srcs, bvec, x, xbuf, N);
    // layer 3
    transform_mfma<<<tgrid, 256, 0, stream>>>(xbuf, WTh, WTl, a_src, a_dst, nullptr,
                                              hbuf, nullptr, as_, ad_, N);
    gat_gather<<<ggrid, 256, 0, stream>>>(hbuf, as_, ad_, offsets, srcs, bvec, x, x3, N);
    // final fc: out = x3 @ fc_w + fc_b
    transform_mfma<<<tgrid, 256, 0, stream>>>(x3, FTh, FTl, nullptr, nullptr, fc_b,
                                              nullptr, out, nullptr, nullptr, N);
}

// Round 12
// 273.808 us; speedup vs baseline: 1.2863x; 1.0039x over previous
//
#include <hip/hip_runtime.h>
#include <hip/hip_bf16.h>
#include <math.h>

#define N_NODES 50000
#define FDIM 64
#define BETA 0.5f
#define NEG_SLOPE 0.2f

typedef __attribute__((ext_vector_type(8))) short bf16x8;
typedef __attribute__((ext_vector_type(4))) float f32x4;

__device__ __forceinline__ unsigned short f2bf(float f) {
    unsigned u = __float_as_uint(f);
    unsigned r = (u + 0x7FFFu + ((u >> 16) & 1u)) >> 16;
    return (unsigned short)r;
}
__device__ __forceinline__ float bf2f(unsigned short s) {
    return __uint_as_float((unsigned)s << 16);
}

// ---------------------------------------------------------------------------
// Histogram of dst buckets (bucket = dst>>8) with per-block int64/int32
// self-detection (odd dwords of int64 data are all zero since N < 2^31).
__global__ __launch_bounds__(256) void hist_kernel(
    const unsigned int* __restrict__ eiu, const int* __restrict__ ei32,
    const long long* __restrict__ ei64, int* __restrict__ bucketCounts, int E) {
    __shared__ int det;
    __shared__ int h[256];
    int t = threadIdx.x;
    if (t == 0) det = 0;
    h[t] = 0;
    __syncthreads();
    unsigned base = blockIdx.x * 256 + t;
    if (base < (unsigned)E && eiu[2 * base + 1] != 0u) atomicOr(&det, 1);
    __syncthreads();
    bool is32 = det != 0;
    for (int i = blockIdx.x * blockDim.x + t; i < E; i += gridDim.x * blockDim.x) {
        int d = is32 ? ei32[E + i] : (int)ei64[E + i];
        atomicAdd(&h[d >> 8], 1);
    }
    __syncthreads();
    if (h[t]) atomicAdd(&bucketCounts[t], h[t]);
}

// Block-aggregated scatter of packed (src | dlow<<16) into bucket regions.
#define CHUNK 4096
__global__ __launch_bounds__(256) void scatter_pairs(
    const unsigned int* __restrict__ eiu, const int* __restrict__ ei32,
    const long long* __restrict__ ei64, const int* __restrict__ bucketCounts,
    int* __restrict__ gCursor, unsigned int* __restrict__ pairs, int E) {
    __shared__ int det;
    __shared__ int sc[256], hist[256], base[256], cur[256];
    int t = threadIdx.x;
    if (t == 0) det = 0;
    hist[t] = 0; cur[t] = 0;
    __syncthreads();
    int beg = blockIdx.x * CHUNK;
    int end = min(E, beg + CHUNK);
    {
        int idx = beg + t;
        if (idx < E && eiu[2 * idx + 1] != 0u) atomicOr(&det, 1);
    }
    int c = bucketCounts[t];
    sc[t] = c;
    __syncthreads();
    bool is32 = det != 0;
    for (int off = 1; off < 256; off <<= 1) {
        int v = (t >= off) ? sc[t - off] : 0;
        __syncthreads();
        sc[t] += v;
        __syncthreads();
    }
    int bucketExcl = sc[t] - c;
    for (int i = beg + t; i < end; i += 256) {
        int d = is32 ? ei32[E + i] : (int)ei64[E + i];
        atomicAdd(&hist[d >> 8], 1);
    }
    __syncthreads();
    if (hist[t] > 0) base[t] = bucketExcl + atomicAdd(&gCursor[t], hist[t]);
    __syncthreads();
    for (int i = beg + t; i < end; i += 256) {
        int s, d;
        if (is32) { s = ei32[i]; d = ei32[E + i]; }
        else      { s = (int)ei64[i]; d = (int)ei64[E + i]; }
        int b = d >> 8;
        int pos = base[b] + atomicAdd(&cur[b], 1);
        pairs[pos] = (unsigned int)s | ((unsigned int)(d & 255) << 16);
    }
}

// One block per bucket: counting sort by full dst; writes per-node offsets + srcs.
__global__ __launch_bounds__(256) void bucket_sort(
    const unsigned int* __restrict__ pairs, const int* __restrict__ bucketCounts,
    int* __restrict__ offsets, int* __restrict__ srcs, int N, int E) {
    __shared__ int scb[256], cnt[256], sc[256], cur[256];
    int b = blockIdx.x, t = threadIdx.x;
    int cb = bucketCounts[t];
    scb[t] = cb;
    __syncthreads();
    for (int off = 1; off < 256; off <<= 1) {
        int v = (t >= off) ? scb[t - off] : 0;
        __syncthreads();
        scb[t] += v;
        __syncthreads();
    }
    int beg = scb[b] - bucketCounts[b];
    int end = scb[b];
    if (b == 0 && t == 0) offsets[N] = E;
    cnt[t] = 0;
    __syncthreads();
    for (int i = beg + t; i < end; i += 256) atomicAdd(&cnt[(pairs[i] >> 16) & 255u], 1);
    __syncthreads();
    sc[t] = cnt[t];
    __syncthreads();
    for (int off = 1; off < 256; off <<= 1) {
        int v = (t >= off) ? sc[t - off] : 0;
        __syncthreads();
        sc[t] += v;
        __syncthreads();
    }
    int excl = sc[t] - cnt[t];
    int node = (b << 8) + t;
    if (node < N) offsets[node] = beg + excl;
    cur[t] = beg + excl;
    __syncthreads();
    for (int i = beg + t; i < end; i += 256) {
        unsigned int p = pairs[i];
        int pos = atomicAdd(&cur[(p >> 16) & 255u], 1);
        srcs[pos] = (int)(p & 0xFFFFu);
    }
}

// ---------------------------------------------------------------------------
// Prep: transpose W and fc_w into bf16 hi/lo, WT[f*64+k] = split(W[k*64+f]).
__global__ __launch_bounds__(256) void prep_weights(
    const float* __restrict__ W, const float* __restrict__ fcw,
    unsigned short* __restrict__ WTh, unsigned short* __restrict__ WTl,
    unsigned short* __restrict__ FTh, unsigned short* __restrict__ FTl) {
    for (int idx = blockIdx.x * 256 + threadIdx.x; idx < 4096; idx += gridDim.x * 256) {
        int k = idx >> 6, f = idx & 63;
        float w = W[idx];
        unsigned short hi = f2bf(w);
        WTh[f * 64 + k] = hi;
        WTl[f * 64 + k] = f2bf(w - bf2f(hi));
        float w2 = fcw[idx];
        unsigned short hi2 = f2bf(w2);
        FTh[f * 64 + k] = hi2;
        FTl[f * 64 + k] = f2bf(w2 - bf2f(hi2));
    }
}

// ---------------------------------------------------------------------------
// Split-bf16 MFMA transform: h = x@W (fp32-accurate via xh*Wh + xh*Wl + xl*Wh).
// hb written CONTIGUOUS: hb[node*64 + f].
__global__ __launch_bounds__(256, 4) void transform_mfma(
    const float* __restrict__ x,
    const unsigned short* __restrict__ WTh, const unsigned short* __restrict__ WTl,
    const float* __restrict__ a_src, const float* __restrict__ a_dst,  // nullable
    const float* __restrict__ bias,                                    // nullable
    unsigned short* __restrict__ hb,  // bf16 out (layers), nullable
    float* __restrict__ fout,         // fp32 out (FC), nullable
    float* __restrict__ as_, float* __restrict__ ad_, int N) {
    __shared__ __align__(16) unsigned short WThs[64 * 72];
    __shared__ __align__(16) unsigned short WTls[64 * 72];
    int tid = threadIdx.x;
    {
        int row = tid >> 2;            // 0..63
        int ch = (tid & 3) * 16;       // shorts
        uint4 h0 = ((const uint4*)(WTh + row * 64 + ch))[0];
        uint4 h1 = ((const uint4*)(WTh + row * 64 + ch))[1];
        uint4 l0 = ((const uint4*)(WTl + row * 64 + ch))[0];
        uint4 l1 = ((const uint4*)(WTl + row * 64 + ch))[1];
        *((uint4*)(WThs + row * 72 + ch)) = h0;
        *((uint4*)(WThs + row * 72 + ch + 8)) = h1;
        *((uint4*)(WTls + row * 72 + ch)) = l0;
        *((uint4*)(WTls + row * 72 + ch + 8)) = l1;
    }

    int wid = tid >> 6;
    int lane = tid & 63;
    int col = lane & 15;
    int quad = lane >> 4;
    int mbase = blockIdx.x * 64 + wid * 16;

    bf16x8 Ah[2], Al[2];
    int arow = mbase + col;
    const float* xr = x + (size_t)(arow < N ? arow : 0) * FDIM + quad * 8;
#pragma unroll
    for (int ks = 0; ks < 2; ks++) {
        float4 xa = *(const float4*)(xr + ks * 32);
        float4 xb = *(const float4*)(xr + ks * 32 + 4);
        float xv[8] = {xa.x, xa.y, xa.z, xa.w, xb.x, xb.y, xb.z, xb.w};
#pragma unroll
        for (int e = 0; e < 8; e++) {
            unsigned short hi = f2bf(xv[e]);
            Ah[ks][e] = (short)hi;
            Al[ks][e] = (short)f2bf(xv[e] - bf2f(hi));
        }
    }
    __syncthreads();

    f32x4 acc[4];
#pragma unroll
    for (int ft = 0; ft < 4; ft++) acc[ft] = (f32x4){0.f, 0.f, 0.f, 0.f};

#pragma unroll
    for (int ft = 0; ft < 4; ft++) {
        int f = ft * 16 + col;
#pragma unroll
        for (int ks = 0; ks < 2; ks++) {
            int off = f * 72 + ks * 32 + quad * 8;
            bf16x8 Bh = *(const bf16x8*)(WThs + off);
            bf16x8 Bl = *(const bf16x8*)(WTls + off);
            acc[ft] = __builtin_amdgcn_mfma_f32_16x16x32_bf16(Ah[ks], Bh, acc[ft], 0, 0, 0);
            acc[ft] = __builtin_amdgcn_mfma_f32_16x16x32_bf16(Ah[ks], Bl, acc[ft], 0, 0, 0);
            acc[ft] = __builtin_amdgcn_mfma_f32_16x16x32_bf16(Al[ks], Bh, acc[ft], 0, 0, 0);
        }
    }

    if (fout) {
#pragma unroll
        for (int ft = 0; ft < 4; ft++) {
            int f = ft * 16 + col;
            float bv = bias ? bias[f] : 0.f;
#pragma unroll
            for (int r = 0; r < 4; r++) {
                int node = mbase + quad * 4 + r;
                if (node < N) fout[(size_t)node * FDIM + f] = acc[ft][r] + bv;
            }
        }
    }
    if (hb) {
#pragma unroll
        for (int ft = 0; ft < 4; ft++) {
            int f = ft * 16 + col;
#pragma unroll
            for (int r = 0; r < 4; r++) {
                int node = mbase + quad * 4 + r;
                if (node < N) hb[(size_t)node * FDIM + f] = f2bf(acc[ft][r]);
            }
        }
    }
    if (as_) {
        float asv[4], adv[4];
#pragma unroll
        for (int ft = 0; ft < 4; ft++) {
            asv[ft] = a_src[ft * 16 + col];
            adv[ft] = a_dst[ft * 16 + col];
        }
#pragma unroll
        for (int r = 0; r < 4; r++) {
            float pa = 0.f, pd = 0.f;
#pragma unroll
            for (int ft = 0; ft < 4; ft++) {
                pa = fmaf(acc[ft][r], asv[ft], pa);
                pd = fmaf(acc[ft][r], adv[ft], pd);
            }
#pragma unroll
            for (int off = 1; off <= 8; off <<= 1) {
                pa += __shfl_xor(pa, off, 64);
                pd += __shfl_xor(pd, off, 64);
            }
            int node = mbase + quad * 4 + r;
            if (col == 0 && node < N) { as_[node] = pa; ad_[node] = pd; }
        }
    }
}

// ---------------------------------------------------------------------------
// One wave per dst node, single-pass fused softmax. 8 edge slots x 8 feature
// lanes; 4-deep software pipeline: 4 LDS pair-reads then 4 dwordx4 row loads
// issued back-to-back (4 outstanding vmem/wave - MLP-bound fix, R11 post-mortem),
// then 32 FMAs. Wave-private LDS staging needs no barrier.
__global__ __launch_bounds__(256) void gat_gather(
    const unsigned short* __restrict__ hb,
    const float* __restrict__ as_, const float* __restrict__ ad_,
    const int* __restrict__ offsets, const int* __restrict__ srcs,
    const float* __restrict__ bvec, const float* __restrict__ x0,
    float* __restrict__ xout, int N) {
    __shared__ __align__(8) float2 stage[4][64];
    int wv = threadIdx.x >> 6;
    int wid = (blockIdx.x * blockDim.x + threadIdx.x) >> 6;
    if (wid >= N) return;
    int lane = threadIdx.x & 63;
    int q = lane & 7;        // feature octet 0..7 (8 bf16 each)
    int eslot = lane >> 3;   // edge slot 0..7
    int beg = offsets[wid], end = offsets[wid + 1];
    float adv = ad_[wid];

    float acc[8];
#pragma unroll
    for (int k = 0; k < 8; k++) acc[k] = 0.f;
    float denom = 0.f;
    const unsigned short* hq = hb + (q << 3);   // + q*8 shorts (16B)
    const float2* sp = &stage[wv][eslot];

#define FMA8(EX, HV)                                                         \
    {                                                                        \
        acc[0] = fmaf(EX, __uint_as_float((HV).x << 16), acc[0]);            \
        acc[1] = fmaf(EX, __uint_as_float((HV).x & 0xFFFF0000u), acc[1]);    \
        acc[2] = fmaf(EX, __uint_as_float((HV).y << 16), acc[2]);            \
        acc[3] = fmaf(EX, __uint_as_float((HV).y & 0xFFFF0000u), acc[3]);    \
        acc[4] = fmaf(EX, __uint_as_float((HV).z << 16), acc[4]);            \
        acc[5] = fmaf(EX, __uint_as_float((HV).z & 0xFFFF0000u), acc[5]);    \
        acc[6] = fmaf(EX, __uint_as_float((HV).w << 16), acc[6]);            \
        acc[7] = fmaf(EX, __uint_as_float((HV).w & 0xFFFF0000u), acc[7]);    \
    }

    for (int cbeg = beg; cbeg < end; cbeg += 64) {
        int i = cbeg + lane;
        float ex = 0.f;
        int s = 0;
        if (i < end) {
            s = srcs[i];
            float e = as_[s] + adv;
            e = e > 0.f ? e : NEG_SLOPE * e;
            ex = __expf(e);
        }
        denom += ex;
        stage[wv][lane] = make_float2(ex, __int_as_float(s));
        int cnt = min(64, end - cbeg);
        int njj = (cnt + 7) >> 3;
        int jj = 0;
        for (; jj + 4 <= njj; jj += 4) {
            float2 p0 = sp[jj * 8];
            float2 p1 = sp[jj * 8 + 8];
            float2 p2 = sp[jj * 8 + 16];
            float2 p3 = sp[jj * 8 + 24];
            uint4 hv0 = *(const uint4*)(hq + ((size_t)__float_as_int(p0.y) << 6));
            uint4 hv1 = *(const uint4*)(hq + ((size_t)__float_as_int(p1.y) << 6));
            uint4 hv2 = *(const uint4*)(hq + ((size_t)__float_as_int(p2.y) << 6));
            uint4 hv3 = *(const uint4*)(hq + ((size_t)__float_as_int(p3.y) << 6));
            FMA8(p0.x, hv0);
            FMA8(p1.x, hv1);
            FMA8(p2.x, hv2);
            FMA8(p3.x, hv3);
        }
        for (; jj < njj; jj++) {
            float2 p0 = sp[jj * 8];
            uint4 hv0 = *(const uint4*)(hq + ((size_t)__float_as_int(p0.y) << 6));
            FMA8(p0.x, hv0);
        }
    }
#undef FMA8

#pragma unroll
    for (int off = 1; off <= 32; off <<= 1) denom += __shfl_xor(denom, off, 64);
#pragma unroll
    for (int off = 8; off <= 32; off <<= 1) {
#pragma unroll
        for (int k = 0; k < 8; k++) acc[k] += __shfl_xor(acc[k], off, 64);
    }
    if (lane < 8) {   // lane == q, eslot == 0: owns features q*8 .. q*8+7
        float inv = denom > 0.f ? 1.f / denom : 0.f;
        int fb = lane * 8;
        f32x4 b0 = *(const f32x4*)(bvec + fb);
        f32x4 b1 = *(const f32x4*)(bvec + fb + 4);
        f32x4 x0a = *(const f32x4*)(x0 + (size_t)wid * FDIM + fb);
        f32x4 x0b = *(const f32x4*)(x0 + (size_t)wid * FDIM + fb + 4);
        f32x4 o0, o1;
        o0.x = BETA * (acc[0] * inv + b0.x) + (1.f - BETA) * x0a.x;
        o0.y = BETA * (acc[1] * inv + b0.y) + (1.f - BETA) * x0a.y;
        o0.z = BETA * (acc[2] * inv + b0.z) + (1.f - BETA) * x0a.z;
        o0.w = BETA * (acc[3] * inv + b0.w) + (1.f - BETA) * x0a.w;
        o1.x = BETA * (acc[4] * inv + b1.x) + (1.f - BETA) * x0b.x;
        o1.y = BETA * (acc[5] * inv + b1.y) + (1.f - BETA) * x0b.y;
        o1.z = BETA * (acc[6] * inv + b1.z) + (1.f - BETA) * x0b.z;
        o1.w = BETA * (acc[7] * inv + b1.w) + (1.f - BETA) * x0b.w;
        *(f32x4*)(xout + (size_t)wid * FDIM + fb) = o0;
        *(f32x4*)(xout + (size_t)wid * FDIM + fb + 4) = o1;
    }
}

// ---------------------------------------------------------------------------
extern "C" void kernel_launch(void* const* d_in, const int* in_sizes, int n_in,
                              void* d_out, int out_size, void* d_ws, size_t ws_size,
                              hipStream_t stream) {
    const int N = N_NODES;
    const int E = in_sizes[1] / 2;
    const int NB = (N + 255) >> 8;   // 196 buckets

    const float* x     = (const float*)d_in[0];
    const void*  ei    = d_in[1];
    const float* W     = (const float*)d_in[2];
    const float* a_src = (const float*)d_in[3];
    const float* a_dst = (const float*)d_in[4];
    const float* bvec  = (const float*)d_in[5];
    const float* fc_w  = (const float*)d_in[6];
    const float* fc_b  = (const float*)d_in[7];

    float* out = (float*)d_out;                 // [N, F]
    float* x3  = out + (size_t)N * FDIM;        // [N, F] (second output = h)

    char* p = (char*)d_ws;
    auto alloc = [&](size_t bytes) -> void* {
        void* r = (void*)p;
        p += (bytes + 255) & ~(size_t)255;
        return r;
    };
    int*            bCounts  = (int*)alloc(512 * 4);   // counts[256] + gCursor[256]
    unsigned int*   pairs    = (unsigned int*)alloc((size_t)E * 4);
    int*            srcs     = (int*)alloc((size_t)E * 4);
    int*            offsets  = (int*)alloc((size_t)(N + 1) * 4);
    float*          as_      = (float*)alloc((size_t)N * 4);
    float*          ad_      = (float*)alloc((size_t)N * 4);
    unsigned short* hbuf     = (unsigned short*)alloc((size_t)N * FDIM * 2);
    float*          xbuf     = (float*)alloc((size_t)N * FDIM * 4);
    unsigned short* WTh      = (unsigned short*)alloc(4096 * 2);
    unsigned short* WTl      = (unsigned short*)alloc(4096 * 2);
    unsigned short* FTh      = (unsigned short*)alloc(4096 * 2);
    unsigned short* FTl      = (unsigned short*)alloc(4096 * 2);
    int* gCursor = bCounts + 256;

    hipMemsetAsync(bCounts, 0, 512 * 4, stream);

    prep_weights<<<16, 256, 0, stream>>>(W, fc_w, WTh, WTl, FTh, FTl);

    hist_kernel<<<512, 256, 0, stream>>>((const unsigned int*)ei, (const int*)ei,
                                         (const long long*)ei, bCounts, E);
    scatter_pairs<<<(E + CHUNK - 1) / CHUNK, 256, 0, stream>>>(
        (const unsigned int*)ei, (const int*)ei, (const long long*)ei,
        bCounts, gCursor, pairs, E);
    bucket_sort<<<NB, 256, 0, stream>>>(pairs, bCounts, offsets, srcs, N, E);

    int tgrid = (N + 63) / 64;
    int ggrid = (N * 64 + 255) / 256;

    // layer 1
    transform_mfma<<<tgrid, 256, 0, stream>>>(x, WTh, WTl, a_src, a_dst, nullptr,
                                              hbuf, nullptr, as_, ad_, N);
    gat_gather<<<ggrid, 256, 0, stream>>>(hbuf, as_, ad_, offsets, srcs, bvec, x, xbuf, N);
    // layer 2
    transform_mfma<<<tgrid, 256, 0, stream>>>(xbuf, WTh, WTl, a_src, a_dst, nullptr,
                                              hbuf, nullptr, as_, ad_, N);
    gat_gather<<<ggrid, 256, 0, stream>>>(hbuf, as_, ad_, offsets, srcs, bvec, x, xbuf, N);
    // layer 3
    transform_mfma<<<tgrid, 256, 0, stream>>>(xbuf, WTh, WTl, a_src, a_dst, nullptr,
                                              hbuf, nullptr, as_, ad_, N);
    gat_gather<<<ggrid, 256, 0, stream>>>(hbuf, as_, ad_, offsets, srcs, bvec, x, x3, N);
    // final fc: out = x3 @ fc_w + fc_b
    transform_mfma<<<tgrid, 256, 0, stream>>>(x3, FTh, FTl, nullptr, nullptr, fc_b,
                                              nullptr, out, nullptr, nullptr, N);
}